// Round 4
// baseline (366.399 us; speedup 1.0000x reference)
//
#include <hip/hip_runtime.h>
#include <cstdint>
#include <cstddef>

#define NEG_ (-1e25f)

typedef __bf16 bf16x8 __attribute__((ext_vector_type(8)));
typedef float  f32x4  __attribute__((ext_vector_type(4)));
typedef short  s16x8  __attribute__((ext_vector_type(8)));
typedef const __attribute__((address_space(1))) void* gas_t;
typedef __attribute__((address_space(3))) void* las_t;

#define MFMA16 __builtin_amdgcn_mfma_f32_16x16x32_bf16

__device__ __forceinline__ short f2bf(float f) {
  union { float f; unsigned u; } v; v.f = f;
  unsigned r = v.u + 0x7fffu + ((v.u >> 16) & 1u);  // RNE
  return (short)(r >> 16);
}

__device__ __forceinline__ s16x8 cvt8(const float* s) {
  bf16x8 r;
  #pragma unroll
  for (int j = 0; j < 8; ++j) r[j] = (__bf16)s[j];  // fptrunc = RNE
  union { bf16x8 b; s16x8 s; } u; u.b = r; return u.s;
}

struct Params {
  const float* ment; const int* ents; const int* msk;
  const float* rm; const float* Wv; const float* bv; const float* Wu;
  const float* bu; const float* Wa; const float* Wr; const float* br;
  const float* Wo; const float* bo; float* out;
  short *Xb, *Wvb, *Wub, *rmb, *Wrb, *Wo2b, *swTb, *Ub, *Weffb, *erb;
  float *wpart, *cf, *gw2;
  unsigned* bar;  // [0]=arrive count, [16]=generation
};

// ---- hand-rolled grid barrier (agent-scope; same mechanism as grid.sync) ----
// All 512 blocks are provably co-resident: launch_bounds(256,2) caps VGPR<=256
// (>=2 waves/EU => 2 blocks/CU) and LDS 49.4KB <= 80KB => 2 blocks/CU; 2*256=512.
__device__ __forceinline__ void gridbar(unsigned* bar, unsigned nb) {
  __syncthreads();
  if (threadIdx.x == 0) {
    unsigned* cnt = bar;
    unsigned* gen = bar + 16;
    unsigned g = __hip_atomic_load(gen, __ATOMIC_RELAXED, __HIP_MEMORY_SCOPE_AGENT);
    __threadfence();  // release: flush this block's stores device-wide
    unsigned v = __hip_atomic_fetch_add(cnt, 1u, __ATOMIC_ACQ_REL, __HIP_MEMORY_SCOPE_AGENT);
    if (v == nb - 1u) {
      __hip_atomic_store(cnt, 0u, __ATOMIC_RELAXED, __HIP_MEMORY_SCOPE_AGENT);
      __hip_atomic_store(gen, g + 1u, __ATOMIC_RELEASE, __HIP_MEMORY_SCOPE_AGENT);
    } else {
      while (__hip_atomic_load(gen, __ATOMIC_ACQUIRE, __HIP_MEMORY_SCOPE_AGENT) == g)
        __builtin_amdgcn_s_sleep(2);
    }
    __threadfence();  // acquire: invalidate caches before reading peers' data
  }
  __syncthreads();
}

// ================= k0: one-pass f32 -> bf16 conversion + barrier init =======
// 4,194,304 floats total = 524288 vec8 units; 131072 threads -> 4 units each.
__global__ __launch_bounds__(256) void k0(Params p) {
  if (blockIdx.x == 0 && threadIdx.x == 0) { p.bar[0] = 0u; p.bar[16] = 0u; }
  const int g = blockIdx.x * 256 + threadIdx.x;
  #pragma unroll
  for (int it = 0; it < 4; ++it) {
    int u = g + it * 131072;
    long e = (long)u * 8;
    const float* src; short* dst;
    if (u < 262144)      { src = p.ment + e;                     dst = p.Xb + e; }
    else if (u < 294912) { long o = e - 2097152; src = p.Wv + o; dst = p.Wvb + o; }
    else if (u < 327680) { long o = e - 2359296; src = p.Wu + o; dst = p.Wub + o; }
    else if (u < 393216) { long o = e - 2621440; src = p.rm + o; dst = p.rmb + o; }
    else if (u < 458752) { long o = e - 3145728; src = p.Wr + o; dst = p.Wrb + o; }
    else                 { long o = e - 3670016;
                           src = p.Wo + (o >> 9) * 1536 + 1024 + (o & 511);
                           dst = p.Wo2b + o; }
    float t[8];
    *(float4*)t       = *(const float4*)src;
    *(float4*)(t + 4) = *(const float4*)(src + 4);
    *(s16x8*)dst = cvt8(t);
  }
}

// ---- dual-A bf16 GEMM, 64x64 tiles, global_load_lds PD=4 ring ----
__device__ void bgemm_dual(const short* __restrict__ A1, const short* __restrict__ A2,
                           long lda, const short* __restrict__ B, long ldb,
                           short* __restrict__ C1, short* __restrict__ C2, int ldc,
                           int NT, int m0, int n0, short* lds) {
  short* As1 = lds;              // 4 bufs * 2048 shorts
  short* As2 = lds + 4 * 2048;
  short* Bs  = lds + 8 * 2048;
  const int tid = threadIdx.x, wave = tid >> 6, lane = tid & 63;
  const int quad = lane >> 4, l16 = lane & 15;
  const int wm = (wave & 1) * 32, wn = (wave >> 1) * 32;
  const int srow = tid >> 2, scol = (tid & 3) * 8;
  const short* A1g = A1 + (long)(m0 + srow) * lda + scol;
  const short* A2g = A2 + (long)(m0 + srow) * lda + scol;
  const short* Bg  = B  + (long)(n0 + srow) * ldb + scol;
  const int ldsoff = wave * 512;
  auto issue = [&](int kt) {
    int buf = kt & 3; int ko = kt * 32;
    __builtin_amdgcn_global_load_lds((gas_t)(A1g + ko), (las_t)(As1 + buf * 2048 + ldsoff), 16, 0, 0);
    __builtin_amdgcn_global_load_lds((gas_t)(A2g + ko), (las_t)(As2 + buf * 2048 + ldsoff), 16, 0, 0);
    __builtin_amdgcn_global_load_lds((gas_t)(Bg  + ko), (las_t)(Bs  + buf * 2048 + ldsoff), 16, 0, 0);
  };
  f32x4 acc1[2][2] = {}, acc2[2][2] = {};
  issue(0); issue(1); issue(2);
  for (int kt = 0; kt < NT; ++kt) {
    int rem = NT - 1 - kt;
    if (rem >= 2)      asm volatile("s_waitcnt vmcnt(6)" ::: "memory");
    else if (rem == 1) asm volatile("s_waitcnt vmcnt(3)" ::: "memory");
    else               asm volatile("s_waitcnt vmcnt(0)" ::: "memory");
    asm volatile("s_barrier" ::: "memory");
    if (kt + 3 < NT) issue(kt + 3);
    const short* as1 = As1 + (kt & 3) * 2048;
    const short* as2 = As2 + (kt & 3) * 2048;
    const short* bs  = Bs  + (kt & 3) * 2048;
    bf16x8 a10 = *(const bf16x8*)&as1[(wm + l16) * 32 + quad * 8];
    bf16x8 a11 = *(const bf16x8*)&as1[(wm + 16 + l16) * 32 + quad * 8];
    bf16x8 a20 = *(const bf16x8*)&as2[(wm + l16) * 32 + quad * 8];
    bf16x8 a21 = *(const bf16x8*)&as2[(wm + 16 + l16) * 32 + quad * 8];
    bf16x8 b0  = *(const bf16x8*)&bs[(wn + l16) * 32 + quad * 8];
    bf16x8 b1  = *(const bf16x8*)&bs[(wn + 16 + l16) * 32 + quad * 8];
    acc1[0][0] = MFMA16(a10, b0, acc1[0][0], 0, 0, 0);
    acc1[0][1] = MFMA16(a10, b1, acc1[0][1], 0, 0, 0);
    acc1[1][0] = MFMA16(a11, b0, acc1[1][0], 0, 0, 0);
    acc1[1][1] = MFMA16(a11, b1, acc1[1][1], 0, 0, 0);
    acc2[0][0] = MFMA16(a20, b0, acc2[0][0], 0, 0, 0);
    acc2[0][1] = MFMA16(a20, b1, acc2[0][1], 0, 0, 0);
    acc2[1][0] = MFMA16(a21, b0, acc2[1][0], 0, 0, 0);
    acc2[1][1] = MFMA16(a21, b1, acc2[1][1], 0, 0, 0);
  }
  #pragma unroll
  for (int i = 0; i < 2; ++i)
    #pragma unroll
    for (int j = 0; j < 2; ++j) {
      int col = n0 + wn + j * 16 + l16;
      #pragma unroll
      for (int r = 0; r < 4; ++r) {
        int row = m0 + wm + i * 16 + quad * 4 + r;
        C1[(long)row * ldc + col] = f2bf(acc1[i][j][r]);
        C2[(long)row * ldc + col] = f2bf(acc2[i][j][r]);
      }
    }
}

// ---- bf16-input 64x64 GEMM: global_load_lds PD=4 ring, ONE barrier/iter ----
template <int EPI>
__device__ void bgemm64(const short* __restrict__ A, int lda,
                        const short* __restrict__ B, int ldb,
                        void* __restrict__ C, int ldc, int NT, int m0, int n0,
                        const float* __restrict__ e0, const float* __restrict__ e1,
                        const float* __restrict__ e2, short* lds) {
  short* As = lds;               // 4 bufs * 2048 shorts
  short* Bs = lds + 4 * 2048;
  const int tid = threadIdx.x;
  const int wave = tid >> 6, lane = tid & 63;
  const int quad = lane >> 4, l16 = lane & 15;
  const int wm = (wave & 1) * 32, wn = (wave >> 1) * 32;
  const int srow = tid >> 2, scol = (tid & 3) * 8;
  const short* Ag = A + (long)(m0 + srow) * lda + scol;
  const short* Bg = B + (long)(n0 + srow) * ldb + scol;
  const int ldsoff = wave * 512;
  auto issue = [&](int kt) {
    int buf = kt & 3; int ko = kt * 32;
    __builtin_amdgcn_global_load_lds((gas_t)(Ag + ko), (las_t)(As + buf * 2048 + ldsoff), 16, 0, 0);
    __builtin_amdgcn_global_load_lds((gas_t)(Bg + ko), (las_t)(Bs + buf * 2048 + ldsoff), 16, 0, 0);
  };
  f32x4 acc[2][2] = {};
  issue(0); issue(1); issue(2);
  for (int kt = 0; kt < NT; ++kt) {
    int rem = NT - 1 - kt;
    if (rem >= 2)      asm volatile("s_waitcnt vmcnt(4)" ::: "memory");
    else if (rem == 1) asm volatile("s_waitcnt vmcnt(2)" ::: "memory");
    else               asm volatile("s_waitcnt vmcnt(0)" ::: "memory");
    asm volatile("s_barrier" ::: "memory");
    if (kt + 3 < NT) issue(kt + 3);
    const short* as = As + (kt & 3) * 2048;
    const short* bs = Bs + (kt & 3) * 2048;
    bf16x8 a0 = *(const bf16x8*)&as[(wm + l16) * 32 + quad * 8];
    bf16x8 a1 = *(const bf16x8*)&as[(wm + 16 + l16) * 32 + quad * 8];
    bf16x8 b0 = *(const bf16x8*)&bs[(wn + l16) * 32 + quad * 8];
    bf16x8 b1 = *(const bf16x8*)&bs[(wn + 16 + l16) * 32 + quad * 8];
    acc[0][0] = MFMA16(a0, b0, acc[0][0], 0, 0, 0);
    acc[0][1] = MFMA16(a0, b1, acc[0][1], 0, 0, 0);
    acc[1][0] = MFMA16(a1, b0, acc[1][0], 0, 0, 0);
    acc[1][1] = MFMA16(a1, b1, acc[1][1], 0, 0, 0);
  }
  #pragma unroll
  for (int i = 0; i < 2; ++i)
    #pragma unroll
    for (int j = 0; j < 2; ++j) {
      int col = n0 + wn + j * 16 + l16;
      #pragma unroll
      for (int r = 0; r < 4; ++r) {
        int row = m0 + wm + i * 16 + quad * 4 + r;
        float v = acc[i][j][r];
        if constexpr (EPI == 1) {
          v += e0[(long)row * 1536 + col];
          ((short*)C)[(long)row * ldc + col] = f2bf(v);
        } else {
          v += e0[col] + e1[row] * e2[col];
          ((float*)C)[(long)row * ldc + col] = v;
        }
      }
    }
}

// ---- gate tile 32(M)x64(N), bf16 inputs, global_load_lds PD=4 ring ----
__device__ void vu_ring(int mi, int ni, const Params& p, short* lds, float* red) {
  short* As  = lds;                       // 4 bufs * 1024 shorts
  short* Bvs = lds + 4 * 1024;            // 4 bufs * 2048
  short* Bus = lds + 4 * 1024 + 4 * 2048; // 4 bufs * 2048
  const int tid = threadIdx.x, wave = tid >> 6, lane = tid & 63;
  const int quad = lane >> 4, l16 = lane & 15;
  const int wm = (wave & 1) * 16, wn = (wave >> 1) * 32;
  const int m0 = mi * 32, n0 = ni * 64;
  const int srow = tid >> 2, scol = (tid & 3) * 8;
  const short* Ag  = p.Xb  + (long)(m0 + srow) * 1024 + scol;  // waves 0-1 only
  const short* Bvg = p.Wvb + (long)(n0 + srow) * 1024 + scol;
  const short* Bug = p.Wub + (long)(n0 + srow) * 1024 + scol;
  const int ldsoff = wave * 512;
  auto issue = [&](int kt) {
    int buf = kt & 3; int ko = kt * 32;
    if (wave < 2)
      __builtin_amdgcn_global_load_lds((gas_t)(Ag + ko), (las_t)(As + buf * 1024 + ldsoff), 16, 0, 0);
    __builtin_amdgcn_global_load_lds((gas_t)(Bvg + ko), (las_t)(Bvs + buf * 2048 + ldsoff), 16, 0, 0);
    __builtin_amdgcn_global_load_lds((gas_t)(Bug + ko), (las_t)(Bus + buf * 2048 + ldsoff), 16, 0, 0);
  };
  f32x4 accv[2] = {}, accu[2] = {};
  issue(0); issue(1); issue(2);
  for (int kt = 0; kt < 32; ++kt) {
    int rem = 31 - kt;
    if (wave < 2) {
      if (rem >= 2)      asm volatile("s_waitcnt vmcnt(6)" ::: "memory");
      else if (rem == 1) asm volatile("s_waitcnt vmcnt(3)" ::: "memory");
      else               asm volatile("s_waitcnt vmcnt(0)" ::: "memory");
    } else {
      if (rem >= 2)      asm volatile("s_waitcnt vmcnt(4)" ::: "memory");
      else if (rem == 1) asm volatile("s_waitcnt vmcnt(2)" ::: "memory");
      else               asm volatile("s_waitcnt vmcnt(0)" ::: "memory");
    }
    asm volatile("s_barrier" ::: "memory");
    if (kt + 3 < 32) issue(kt + 3);
    const short* as  = As  + (kt & 3) * 1024;
    const short* bvs = Bvs + (kt & 3) * 2048;
    const short* bus = Bus + (kt & 3) * 2048;
    bf16x8 af = *(const bf16x8*)&as[(wm + l16) * 32 + quad * 8];
    bf16x8 v0 = *(const bf16x8*)&bvs[(wn + l16) * 32 + quad * 8];
    bf16x8 v1 = *(const bf16x8*)&bvs[(wn + 16 + l16) * 32 + quad * 8];
    bf16x8 u0 = *(const bf16x8*)&bus[(wn + l16) * 32 + quad * 8];
    bf16x8 u1 = *(const bf16x8*)&bus[(wn + 16 + l16) * 32 + quad * 8];
    accv[0] = MFMA16(af, v0, accv[0], 0, 0, 0);
    accv[1] = MFMA16(af, v1, accv[1], 0, 0, 0);
    accu[0] = MFMA16(af, u0, accu[0], 0, 0, 0);
    accu[1] = MFMA16(af, u1, accu[1], 0, 0, 0);
  }
  float wsum[4] = {0.f, 0.f, 0.f, 0.f};
  #pragma unroll
  for (int j = 0; j < 2; ++j) {
    int col = n0 + wn + j * 16 + l16;
    float bvc = p.bv[col], buc = p.bu[col], wac = p.Wa[col];
    #pragma unroll
    for (int r = 0; r < 4; ++r) {
      float vv = tanhf(accv[j][r] + bvc);
      float uu = accu[j][r] + buc;
      wsum[r] += (vv / (1.0f + expf(-uu))) * wac;
    }
  }
  #pragma unroll
  for (int r = 0; r < 4; ++r) {
    float s = wsum[r];
    s += __shfl_down(s, 8, 16);
    s += __shfl_down(s, 4, 16);
    s += __shfl_down(s, 2, 16);
    s += __shfl_down(s, 1, 16);
    if (l16 == 0) red[(wave >> 1) * 32 + wm + quad * 4 + r] = s;
  }
  __syncthreads();
  if (tid < 32) p.wpart[ni * 2048 + m0 + tid] = red[tid] + red[32 + tid];
}

// ---- gw2 rowsum, one row per wave ----
__device__ void gw2_wave(int row, const Params& p) {
  const int lane = threadIdx.x & 63;
  const short* u = p.Ub + (long)row * 1024 + lane * 16;
  union { s16x8 s; bf16x8 b; } w0, w1;
  w0.s = *(const s16x8*)u;
  w1.s = *(const s16x8*)(u + 8);
  float s = 0.f;
  #pragma unroll
  for (int j = 0; j < 8; ++j) s += (float)w0.b[j] + (float)w1.b[j];
  #pragma unroll
  for (int off = 32; off > 0; off >>= 1) s += __shfl_down(s, off);
  if (lane == 0) p.gw2[row] = s;
}

// ---- masked softmax over K=16 + pooling, ONE WAVE per entity (no LDS) ----
__device__ void entity_wave(int be, const Params& p) {
  const int lane = threadIdx.x & 63;
  const int b = be >> 7;  // E=128
  float a = NEG_; int idx = 0;
  if (lane < 16) {
    idx = p.ents[be * 16 + lane];
    int j = (b << 8) + idx;
    float lw = p.wpart[j] + p.wpart[2048 + j] + p.wpart[4096 + j] + p.wpart[6144 + j];
    a = p.msk[be * 16 + lane] ? lw : NEG_;
  }
  float m = a;
  m = fmaxf(m, __shfl_xor(m, 1, 16));
  m = fmaxf(m, __shfl_xor(m, 2, 16));
  m = fmaxf(m, __shfl_xor(m, 4, 16));
  m = fmaxf(m, __shfl_xor(m, 8, 16));
  float e = expf(a - m);
  float s = e;
  s += __shfl_xor(s, 1, 16);
  s += __shfl_xor(s, 2, 16);
  s += __shfl_xor(s, 4, 16);
  s += __shfl_xor(s, 8, 16);
  float aw = e / s;  // valid on lanes 0-15
  const float* Xr = p.ment + ((long)b << 18);
  const int h0 = lane * 16;
  float acc[16];
  #pragma unroll
  for (int t = 0; t < 16; ++t) acc[t] = 0.f;
  #pragma unroll
  for (int k = 0; k < 16; ++k) {
    float ak = __shfl(aw, k);
    int   ik = __shfl(idx, k);
    const float* xr = Xr + (long)ik * 1024 + h0;
    f32x4 x0 = *(const f32x4*)(xr);
    f32x4 x1 = *(const f32x4*)(xr + 4);
    f32x4 x2 = *(const f32x4*)(xr + 8);
    f32x4 x3 = *(const f32x4*)(xr + 12);
    #pragma unroll
    for (int t = 0; t < 4; ++t) {
      acc[t]      += ak * x0[t];
      acc[4 + t]  += ak * x1[t];
      acc[8 + t]  += ak * x2[t];
      acc[12 + t] += ak * x3[t];
    }
  }
  short* er = p.erb + (long)be * 1024 + h0;
  *(s16x8*)er       = cvt8(acc);
  *(s16x8*)(er + 8) = cvt8(acc + 8);
  float c = 0.f;
  const float* brp = p.br + h0;
  #pragma unroll
  for (int t = 0; t < 16; ++t) c += acc[t] * brp[t];
  #pragma unroll
  for (int off = 32; off > 0; off >>= 1) c += __shfl_down(c, off);
  if (lane == 0) p.cf[be] = c;
}

// ========== kF: phases 1-3 fused with in-kernel grid barriers ==========
__global__ __launch_bounds__(256, 2) void kF(Params p) {
  __shared__ short lds[24576];  // 48 KB (dual: 3 slabs x 4 bufs; vu: 40 KB)
  __shared__ float red[64];
  const int blk = blockIdx.x;

  // phase 1: dual gemm {s_wT = Wr@rm^T, U = Wo2@rm^T} | gate gemm
  if (blk < 256) {
    bgemm_dual(p.Wrb, p.Wo2b, 512, p.rmb, 512, p.swTb, p.Ub, 1024, 16,
               (blk >> 4) * 64, (blk & 15) * 64, lds);
  } else {
    int q = blk - 256;  // ni-outer: same-X blocks spread rows
    vu_ring(q & 63, q >> 6, p, lds, red);
  }
  gridbar(p.bar, 512);

  // phase 2: Weff = Wo1 + U@s_wT^T | gw2 rowsum + wave-parallel softmax
  if (blk < 256) {
    bgemm64<1>(p.Ub, 1024, p.swTb, 1024, p.Weffb, 1024, 32,
               (blk >> 4) * 64, (blk & 15) * 64, p.Wo, nullptr, nullptr, lds);
  } else {
    int q = blk - 256;
    int wave = threadIdx.x >> 6;
    gw2_wave(q * 4 + wave, p);
    entity_wave(q * 4 + wave, p);
  }
  gridbar(p.bar, 512);

  // phase 3: out = er @ Weff^T + bo + cf*gw2 (blocks 256+ exit)
  if (blk < 256) {
    bgemm64<2>(p.erb, 1024, p.Weffb, 1024, p.out, 1024, 32,
               (blk >> 4) * 64, (blk & 15) * 64, p.bo, p.cf, p.gw2, lds);
  }
}

extern "C" void kernel_launch(void* const* d_in, const int* in_sizes, int n_in,
                              void* d_out, int out_size, void* d_ws, size_t ws_size,
                              hipStream_t stream) {
  (void)in_sizes; (void)n_in; (void)out_size; (void)ws_size;
  Params p;
  p.ment = (const float*)d_in[0];
  p.ents = (const int*)d_in[1];
  p.msk  = (const int*)d_in[2];
  p.rm   = (const float*)d_in[3];
  p.Wv   = (const float*)d_in[4];
  p.bv   = (const float*)d_in[5];
  p.Wu   = (const float*)d_in[6];
  p.bu   = (const float*)d_in[7];
  p.Wa   = (const float*)d_in[8];
  // d_in[9] = ba: drops out (softmax shift-invariance)
  p.Wr   = (const float*)d_in[10];
  p.br   = (const float*)d_in[11];
  p.Wo   = (const float*)d_in[12];
  p.bo   = (const float*)d_in[13];
  p.out  = (float*)d_out;

  char* w = (char*)d_ws;
  auto alloc = [&](size_t bytes) {
    void* q = (void*)w; w += (bytes + 255) & ~(size_t)255; return q;
  };
  p.Xb    = (short*)alloc((size_t)2048 * 1024 * 2);  // X bf16
  p.Wvb   = (short*)alloc((size_t)256 * 1024 * 2);
  p.Wub   = (short*)alloc((size_t)256 * 1024 * 2);
  p.rmb   = (short*)alloc((size_t)1024 * 512 * 2);
  p.Wrb   = (short*)alloc((size_t)1024 * 512 * 2);
  p.Wo2b  = (short*)alloc((size_t)1024 * 512 * 2);
  p.swTb  = (short*)alloc((size_t)1024 * 1024 * 2);  // s_wT[h,r] bf16
  p.Ub    = (short*)alloc((size_t)1024 * 1024 * 2);  // U[h,r] bf16
  p.Weffb = (short*)alloc((size_t)1024 * 1024 * 2);  // Wo1 + U@s_wT^T bf16
  p.erb   = (short*)alloc((size_t)1024 * 1024 * 2);  // entity reprs bf16
  p.wpart = (float*)alloc((size_t)4 * 2048 * 4);     // gate partials
  p.cf    = (float*)alloc((size_t)1024 * 4);         // er . br
  p.gw2   = (float*)alloc((size_t)1024 * 4);         // rowsum(U)
  p.bar   = (unsigned*)alloc(256);                   // grid barrier state

  k0<<<512, 256, 0, stream>>>(p);   // convert + zero barrier words
  kF<<<512, 256, 0, stream>>>(p);   // phases 1-3 with in-kernel grid sync
}

// Round 5
// 174.332 us; speedup vs baseline: 2.1017x; 2.1017x over previous
//
#include <hip/hip_runtime.h>
#include <cstdint>
#include <cstddef>

#define NEG_ (-1e25f)

typedef __bf16 bf16x8 __attribute__((ext_vector_type(8)));
typedef float  f32x4  __attribute__((ext_vector_type(4)));
typedef short  s16x8  __attribute__((ext_vector_type(8)));
typedef const __attribute__((address_space(1))) void* gas_t;
typedef __attribute__((address_space(3))) void* las_t;

#define MFMA16 __builtin_amdgcn_mfma_f32_16x16x32_bf16

__device__ __forceinline__ short f2bf(float f) {
  union { float f; unsigned u; } v; v.f = f;
  unsigned r = v.u + 0x7fffu + ((v.u >> 16) & 1u);  // RNE
  return (short)(r >> 16);
}

__device__ __forceinline__ s16x8 cvt8(const float* s) {
  bf16x8 r;
  #pragma unroll
  for (int j = 0; j < 8; ++j) r[j] = (__bf16)s[j];  // fptrunc = RNE
  union { bf16x8 b; s16x8 s; } u; u.b = r; return u.s;
}

struct Params {
  const float* ment; const int* ents; const int* msk;
  const float* rm; const float* Wv; const float* bv; const float* Wu;
  const float* bu; const float* Wa; const float* Wr; const float* br;
  const float* Wo; const float* bo; float* out;
  short *Xb, *Wvb, *Wub, *rmb, *Wrb, *Wo2b, *swTb, *Ub, *Weffb, *erb;
  float *wpart, *cf, *gw2;
  unsigned* bar;  // [0]=arrive count, [32]=generation (separate 128B lines)
};

// ---- grid barrier, cache-storm-free protocol ----
// R4 lesson: ACQUIRE loads in the spin loop emit buffer_inv PER POLL (512
// blocks x 1000s of polls = chip-wide invalidate storm, 292us). Correct
// protocol: release is carried by the arrival RMW (one wbl2), spin is
// RELAXED (coherence-point read, no cache ops), ONE acquire fence on exit.
__device__ __forceinline__ void gridbar(unsigned* bar, unsigned nb, bool wait) {
  __syncthreads();
  if (threadIdx.x == 0) {
    unsigned* cnt = bar;
    unsigned* gen = bar + 32;
    unsigned g = __hip_atomic_load(gen, __ATOMIC_RELAXED, __HIP_MEMORY_SCOPE_AGENT);
    // RELEASE RMW: flushes this block's prior stores to the coherence point.
    unsigned v = __hip_atomic_fetch_add(cnt, 1u, __ATOMIC_RELEASE, __HIP_MEMORY_SCOPE_AGENT);
    if (v == nb - 1u) {
      __hip_atomic_store(cnt, 0u, __ATOMIC_RELAXED, __HIP_MEMORY_SCOPE_AGENT);
      // RELEASE orders the cnt reset before the gen bump.
      __hip_atomic_store(gen, g + 1u, __ATOMIC_RELEASE, __HIP_MEMORY_SCOPE_AGENT);
    } else if (wait) {
      while (__hip_atomic_load(gen, __ATOMIC_RELAXED, __HIP_MEMORY_SCOPE_AGENT) == g)
        __builtin_amdgcn_s_sleep(16);
    }
    // single acquire: invalidate stale local caches before reading peers' data
    __builtin_amdgcn_fence(__ATOMIC_ACQUIRE, "agent");
  }
  __syncthreads();
}

// ================= k0: one-pass f32 -> bf16 conversion + barrier init =======
__global__ __launch_bounds__(256) void k0(Params p) {
  if (blockIdx.x == 0 && threadIdx.x == 0) { p.bar[0] = 0u; p.bar[32] = 0u; }
  const int g = blockIdx.x * 256 + threadIdx.x;
  #pragma unroll
  for (int it = 0; it < 4; ++it) {
    int u = g + it * 131072;
    long e = (long)u * 8;
    const float* src; short* dst;
    if (u < 262144)      { src = p.ment + e;                     dst = p.Xb + e; }
    else if (u < 294912) { long o = e - 2097152; src = p.Wv + o; dst = p.Wvb + o; }
    else if (u < 327680) { long o = e - 2359296; src = p.Wu + o; dst = p.Wub + o; }
    else if (u < 393216) { long o = e - 2621440; src = p.rm + o; dst = p.rmb + o; }
    else if (u < 458752) { long o = e - 3145728; src = p.Wr + o; dst = p.Wrb + o; }
    else                 { long o = e - 3670016;
                           src = p.Wo + (o >> 9) * 1536 + 1024 + (o & 511);
                           dst = p.Wo2b + o; }
    float t[8];
    *(float4*)t       = *(const float4*)src;
    *(float4*)(t + 4) = *(const float4*)(src + 4);
    *(s16x8*)dst = cvt8(t);
  }
}

// ---- dual-A bf16 GEMM, 64x64 tiles, global_load_lds PD=4 ring ----
__device__ void bgemm_dual(const short* __restrict__ A1, const short* __restrict__ A2,
                           long lda, const short* __restrict__ B, long ldb,
                           short* __restrict__ C1, short* __restrict__ C2, int ldc,
                           int NT, int m0, int n0, short* lds) {
  short* As1 = lds;              // 4 bufs * 2048 shorts
  short* As2 = lds + 4 * 2048;
  short* Bs  = lds + 8 * 2048;
  const int tid = threadIdx.x, wave = tid >> 6, lane = tid & 63;
  const int quad = lane >> 4, l16 = lane & 15;
  const int wm = (wave & 1) * 32, wn = (wave >> 1) * 32;
  const int srow = tid >> 2, scol = (tid & 3) * 8;
  const short* A1g = A1 + (long)(m0 + srow) * lda + scol;
  const short* A2g = A2 + (long)(m0 + srow) * lda + scol;
  const short* Bg  = B  + (long)(n0 + srow) * ldb + scol;
  const int ldsoff = wave * 512;
  auto issue = [&](int kt) {
    int buf = kt & 3; int ko = kt * 32;
    __builtin_amdgcn_global_load_lds((gas_t)(A1g + ko), (las_t)(As1 + buf * 2048 + ldsoff), 16, 0, 0);
    __builtin_amdgcn_global_load_lds((gas_t)(A2g + ko), (las_t)(As2 + buf * 2048 + ldsoff), 16, 0, 0);
    __builtin_amdgcn_global_load_lds((gas_t)(Bg  + ko), (las_t)(Bs  + buf * 2048 + ldsoff), 16, 0, 0);
  };
  f32x4 acc1[2][2] = {}, acc2[2][2] = {};
  issue(0); issue(1); issue(2);
  for (int kt = 0; kt < NT; ++kt) {
    int rem = NT - 1 - kt;
    if (rem >= 2)      asm volatile("s_waitcnt vmcnt(6)" ::: "memory");
    else if (rem == 1) asm volatile("s_waitcnt vmcnt(3)" ::: "memory");
    else               asm volatile("s_waitcnt vmcnt(0)" ::: "memory");
    asm volatile("s_barrier" ::: "memory");
    if (kt + 3 < NT) issue(kt + 3);
    const short* as1 = As1 + (kt & 3) * 2048;
    const short* as2 = As2 + (kt & 3) * 2048;
    const short* bs  = Bs  + (kt & 3) * 2048;
    bf16x8 a10 = *(const bf16x8*)&as1[(wm + l16) * 32 + quad * 8];
    bf16x8 a11 = *(const bf16x8*)&as1[(wm + 16 + l16) * 32 + quad * 8];
    bf16x8 a20 = *(const bf16x8*)&as2[(wm + l16) * 32 + quad * 8];
    bf16x8 a21 = *(const bf16x8*)&as2[(wm + 16 + l16) * 32 + quad * 8];
    bf16x8 b0  = *(const bf16x8*)&bs[(wn + l16) * 32 + quad * 8];
    bf16x8 b1  = *(const bf16x8*)&bs[(wn + 16 + l16) * 32 + quad * 8];
    acc1[0][0] = MFMA16(a10, b0, acc1[0][0], 0, 0, 0);
    acc1[0][1] = MFMA16(a10, b1, acc1[0][1], 0, 0, 0);
    acc1[1][0] = MFMA16(a11, b0, acc1[1][0], 0, 0, 0);
    acc1[1][1] = MFMA16(a11, b1, acc1[1][1], 0, 0, 0);
    acc2[0][0] = MFMA16(a20, b0, acc2[0][0], 0, 0, 0);
    acc2[0][1] = MFMA16(a20, b1, acc2[0][1], 0, 0, 0);
    acc2[1][0] = MFMA16(a21, b0, acc2[1][0], 0, 0, 0);
    acc2[1][1] = MFMA16(a21, b1, acc2[1][1], 0, 0, 0);
  }
  #pragma unroll
  for (int i = 0; i < 2; ++i)
    #pragma unroll
    for (int j = 0; j < 2; ++j) {
      int col = n0 + wn + j * 16 + l16;
      #pragma unroll
      for (int r = 0; r < 4; ++r) {
        int row = m0 + wm + i * 16 + quad * 4 + r;
        C1[(long)row * ldc + col] = f2bf(acc1[i][j][r]);
        C2[(long)row * ldc + col] = f2bf(acc2[i][j][r]);
      }
    }
}

// ---- bf16-input 64x64 GEMM: global_load_lds PD=4 ring, ONE barrier/iter ----
template <int EPI>
__device__ void bgemm64(const short* __restrict__ A, int lda,
                        const short* __restrict__ B, int ldb,
                        void* __restrict__ C, int ldc, int NT, int m0, int n0,
                        const float* __restrict__ e0, const float* __restrict__ e1,
                        const float* __restrict__ e2, short* lds) {
  short* As = lds;               // 4 bufs * 2048 shorts
  short* Bs = lds + 4 * 2048;
  const int tid = threadIdx.x;
  const int wave = tid >> 6, lane = tid & 63;
  const int quad = lane >> 4, l16 = lane & 15;
  const int wm = (wave & 1) * 32, wn = (wave >> 1) * 32;
  const int srow = tid >> 2, scol = (tid & 3) * 8;
  const short* Ag = A + (long)(m0 + srow) * lda + scol;
  const short* Bg = B + (long)(n0 + srow) * ldb + scol;
  const int ldsoff = wave * 512;
  auto issue = [&](int kt) {
    int buf = kt & 3; int ko = kt * 32;
    __builtin_amdgcn_global_load_lds((gas_t)(Ag + ko), (las_t)(As + buf * 2048 + ldsoff), 16, 0, 0);
    __builtin_amdgcn_global_load_lds((gas_t)(Bg + ko), (las_t)(Bs + buf * 2048 + ldsoff), 16, 0, 0);
  };
  f32x4 acc[2][2] = {};
  issue(0); issue(1); issue(2);
  for (int kt = 0; kt < NT; ++kt) {
    int rem = NT - 1 - kt;
    if (rem >= 2)      asm volatile("s_waitcnt vmcnt(4)" ::: "memory");
    else if (rem == 1) asm volatile("s_waitcnt vmcnt(2)" ::: "memory");
    else               asm volatile("s_waitcnt vmcnt(0)" ::: "memory");
    asm volatile("s_barrier" ::: "memory");
    if (kt + 3 < NT) issue(kt + 3);
    const short* as = As + (kt & 3) * 2048;
    const short* bs = Bs + (kt & 3) * 2048;
    bf16x8 a0 = *(const bf16x8*)&as[(wm + l16) * 32 + quad * 8];
    bf16x8 a1 = *(const bf16x8*)&as[(wm + 16 + l16) * 32 + quad * 8];
    bf16x8 b0 = *(const bf16x8*)&bs[(wn + l16) * 32 + quad * 8];
    bf16x8 b1 = *(const bf16x8*)&bs[(wn + 16 + l16) * 32 + quad * 8];
    acc[0][0] = MFMA16(a0, b0, acc[0][0], 0, 0, 0);
    acc[0][1] = MFMA16(a0, b1, acc[0][1], 0, 0, 0);
    acc[1][0] = MFMA16(a1, b0, acc[1][0], 0, 0, 0);
    acc[1][1] = MFMA16(a1, b1, acc[1][1], 0, 0, 0);
  }
  #pragma unroll
  for (int i = 0; i < 2; ++i)
    #pragma unroll
    for (int j = 0; j < 2; ++j) {
      int col = n0 + wn + j * 16 + l16;
      #pragma unroll
      for (int r = 0; r < 4; ++r) {
        int row = m0 + wm + i * 16 + quad * 4 + r;
        float v = acc[i][j][r];
        if constexpr (EPI == 1) {
          v += e0[(long)row * 1536 + col];
          ((short*)C)[(long)row * ldc + col] = f2bf(v);
        } else {
          v += e0[col] + e1[row] * e2[col];
          ((float*)C)[(long)row * ldc + col] = v;
        }
      }
    }
}

// ---- gate tile 32(M)x64(N), bf16 inputs, global_load_lds PD=4 ring ----
__device__ void vu_ring(int mi, int ni, const Params& p, short* lds, float* red) {
  short* As  = lds;                       // 4 bufs * 1024 shorts
  short* Bvs = lds + 4 * 1024;            // 4 bufs * 2048
  short* Bus = lds + 4 * 1024 + 4 * 2048; // 4 bufs * 2048
  const int tid = threadIdx.x, wave = tid >> 6, lane = tid & 63;
  const int quad = lane >> 4, l16 = lane & 15;
  const int wm = (wave & 1) * 16, wn = (wave >> 1) * 32;
  const int m0 = mi * 32, n0 = ni * 64;
  const int srow = tid >> 2, scol = (tid & 3) * 8;
  const short* Ag  = p.Xb  + (long)(m0 + srow) * 1024 + scol;  // waves 0-1 only
  const short* Bvg = p.Wvb + (long)(n0 + srow) * 1024 + scol;
  const short* Bug = p.Wub + (long)(n0 + srow) * 1024 + scol;
  const int ldsoff = wave * 512;
  auto issue = [&](int kt) {
    int buf = kt & 3; int ko = kt * 32;
    if (wave < 2)
      __builtin_amdgcn_global_load_lds((gas_t)(Ag + ko), (las_t)(As + buf * 1024 + ldsoff), 16, 0, 0);
    __builtin_amdgcn_global_load_lds((gas_t)(Bvg + ko), (las_t)(Bvs + buf * 2048 + ldsoff), 16, 0, 0);
    __builtin_amdgcn_global_load_lds((gas_t)(Bug + ko), (las_t)(Bus + buf * 2048 + ldsoff), 16, 0, 0);
  };
  f32x4 accv[2] = {}, accu[2] = {};
  issue(0); issue(1); issue(2);
  for (int kt = 0; kt < 32; ++kt) {
    int rem = 31 - kt;
    if (wave < 2) {
      if (rem >= 2)      asm volatile("s_waitcnt vmcnt(6)" ::: "memory");
      else if (rem == 1) asm volatile("s_waitcnt vmcnt(3)" ::: "memory");
      else               asm volatile("s_waitcnt vmcnt(0)" ::: "memory");
    } else {
      if (rem >= 2)      asm volatile("s_waitcnt vmcnt(4)" ::: "memory");
      else if (rem == 1) asm volatile("s_waitcnt vmcnt(2)" ::: "memory");
      else               asm volatile("s_waitcnt vmcnt(0)" ::: "memory");
    }
    asm volatile("s_barrier" ::: "memory");
    if (kt + 3 < 32) issue(kt + 3);
    const short* as  = As  + (kt & 3) * 1024;
    const short* bvs = Bvs + (kt & 3) * 2048;
    const short* bus = Bus + (kt & 3) * 2048;
    bf16x8 af = *(const bf16x8*)&as[(wm + l16) * 32 + quad * 8];
    bf16x8 v0 = *(const bf16x8*)&bvs[(wn + l16) * 32 + quad * 8];
    bf16x8 v1 = *(const bf16x8*)&bvs[(wn + 16 + l16) * 32 + quad * 8];
    bf16x8 u0 = *(const bf16x8*)&bus[(wn + l16) * 32 + quad * 8];
    bf16x8 u1 = *(const bf16x8*)&bus[(wn + 16 + l16) * 32 + quad * 8];
    accv[0] = MFMA16(af, v0, accv[0], 0, 0, 0);
    accv[1] = MFMA16(af, v1, accv[1], 0, 0, 0);
    accu[0] = MFMA16(af, u0, accu[0], 0, 0, 0);
    accu[1] = MFMA16(af, u1, accu[1], 0, 0, 0);
  }
  float wsum[4] = {0.f, 0.f, 0.f, 0.f};
  #pragma unroll
  for (int j = 0; j < 2; ++j) {
    int col = n0 + wn + j * 16 + l16;
    float bvc = p.bv[col], buc = p.bu[col], wac = p.Wa[col];
    #pragma unroll
    for (int r = 0; r < 4; ++r) {
      float vv = tanhf(accv[j][r] + bvc);
      float uu = accu[j][r] + buc;
      wsum[r] += (vv / (1.0f + expf(-uu))) * wac;
    }
  }
  #pragma unroll
  for (int r = 0; r < 4; ++r) {
    float s = wsum[r];
    s += __shfl_down(s, 8, 16);
    s += __shfl_down(s, 4, 16);
    s += __shfl_down(s, 2, 16);
    s += __shfl_down(s, 1, 16);
    if (l16 == 0) red[(wave >> 1) * 32 + wm + quad * 4 + r] = s;
  }
  __syncthreads();
  if (tid < 32) p.wpart[ni * 2048 + m0 + tid] = red[tid] + red[32 + tid];
}

// ---- gw2 rowsum, one row per wave ----
__device__ void gw2_wave(int row, const Params& p) {
  const int lane = threadIdx.x & 63;
  const short* u = p.Ub + (long)row * 1024 + lane * 16;
  union { s16x8 s; bf16x8 b; } w0, w1;
  w0.s = *(const s16x8*)u;
  w1.s = *(const s16x8*)(u + 8);
  float s = 0.f;
  #pragma unroll
  for (int j = 0; j < 8; ++j) s += (float)w0.b[j] + (float)w1.b[j];
  #pragma unroll
  for (int off = 32; off > 0; off >>= 1) s += __shfl_down(s, off);
  if (lane == 0) p.gw2[row] = s;
}

// ---- masked softmax over K=16 + pooling, ONE WAVE per entity (no LDS) ----
__device__ void entity_wave(int be, const Params& p) {
  const int lane = threadIdx.x & 63;
  const int b = be >> 7;  // E=128
  float a = NEG_; int idx = 0;
  if (lane < 16) {
    idx = p.ents[be * 16 + lane];
    int j = (b << 8) + idx;
    float lw = p.wpart[j] + p.wpart[2048 + j] + p.wpart[4096 + j] + p.wpart[6144 + j];
    a = p.msk[be * 16 + lane] ? lw : NEG_;
  }
  float m = a;
  m = fmaxf(m, __shfl_xor(m, 1, 16));
  m = fmaxf(m, __shfl_xor(m, 2, 16));
  m = fmaxf(m, __shfl_xor(m, 4, 16));
  m = fmaxf(m, __shfl_xor(m, 8, 16));
  float e = expf(a - m);
  float s = e;
  s += __shfl_xor(s, 1, 16);
  s += __shfl_xor(s, 2, 16);
  s += __shfl_xor(s, 4, 16);
  s += __shfl_xor(s, 8, 16);
  float aw = e / s;  // valid on lanes 0-15
  const float* Xr = p.ment + ((long)b << 18);
  const int h0 = lane * 16;
  float acc[16];
  #pragma unroll
  for (int t = 0; t < 16; ++t) acc[t] = 0.f;
  #pragma unroll
  for (int k = 0; k < 16; ++k) {
    float ak = __shfl(aw, k);
    int   ik = __shfl(idx, k);
    const float* xr = Xr + (long)ik * 1024 + h0;
    f32x4 x0 = *(const f32x4*)(xr);
    f32x4 x1 = *(const f32x4*)(xr + 4);
    f32x4 x2 = *(const f32x4*)(xr + 8);
    f32x4 x3 = *(const f32x4*)(xr + 12);
    #pragma unroll
    for (int t = 0; t < 4; ++t) {
      acc[t]      += ak * x0[t];
      acc[4 + t]  += ak * x1[t];
      acc[8 + t]  += ak * x2[t];
      acc[12 + t] += ak * x3[t];
    }
  }
  short* er = p.erb + (long)be * 1024 + h0;
  *(s16x8*)er       = cvt8(acc);
  *(s16x8*)(er + 8) = cvt8(acc + 8);
  float c = 0.f;
  const float* brp = p.br + h0;
  #pragma unroll
  for (int t = 0; t < 16; ++t) c += acc[t] * brp[t];
  #pragma unroll
  for (int off = 32; off > 0; off >>= 1) c += __shfl_down(c, off);
  if (lane == 0) p.cf[be] = c;
}

// ========== kF: phases 1-3 fused with in-kernel grid barriers ==========
__global__ __launch_bounds__(256, 2) void kF(Params p) {
  __shared__ short lds[24576];  // 48 KB (dual: 3 slabs x 4 bufs; vu: 40 KB)
  __shared__ float red[64];
  const int blk = blockIdx.x;

  // phase 1: dual gemm {s_wT = Wr@rm^T, U = Wo2@rm^T} | gate gemm
  if (blk < 256) {
    bgemm_dual(p.Wrb, p.Wo2b, 512, p.rmb, 512, p.swTb, p.Ub, 1024, 16,
               (blk >> 4) * 64, (blk & 15) * 64, lds);
  } else {
    int q = blk - 256;  // ni-outer: same-X blocks spread rows
    vu_ring(q & 63, q >> 6, p, lds, red);
  }
  gridbar(p.bar, 512, true);

  // phase 2: Weff = Wo1 + U@s_wT^T | gw2 rowsum + wave-parallel softmax
  if (blk < 256) {
    bgemm64<1>(p.Ub, 1024, p.swTb, 1024, p.Weffb, 1024, 32,
               (blk >> 4) * 64, (blk & 15) * 64, p.Wo, nullptr, nullptr, lds);
  } else {
    int q = blk - 256;
    int wave = threadIdx.x >> 6;
    gw2_wave(q * 4 + wave, p);
    entity_wave(q * 4 + wave, p);
  }
  // blocks 256-511 arrive-only (release their stores) and exit, freeing CUs
  gridbar(p.bar, 512, blk < 256);

  // phase 3: out = er @ Weff^T + bo + cf*gw2
  if (blk < 256) {
    bgemm64<2>(p.erb, 1024, p.Weffb, 1024, p.out, 1024, 32,
               (blk >> 4) * 64, (blk & 15) * 64, p.bo, p.cf, p.gw2, lds);
  }
}

extern "C" void kernel_launch(void* const* d_in, const int* in_sizes, int n_in,
                              void* d_out, int out_size, void* d_ws, size_t ws_size,
                              hipStream_t stream) {
  (void)in_sizes; (void)n_in; (void)out_size; (void)ws_size;
  Params p;
  p.ment = (const float*)d_in[0];
  p.ents = (const int*)d_in[1];
  p.msk  = (const int*)d_in[2];
  p.rm   = (const float*)d_in[3];
  p.Wv   = (const float*)d_in[4];
  p.bv   = (const float*)d_in[5];
  p.Wu   = (const float*)d_in[6];
  p.bu   = (const float*)d_in[7];
  p.Wa   = (const float*)d_in[8];
  // d_in[9] = ba: drops out (softmax shift-invariance)
  p.Wr   = (const float*)d_in[10];
  p.br   = (const float*)d_in[11];
  p.Wo   = (const float*)d_in[12];
  p.bo   = (const float*)d_in[13];
  p.out  = (float*)d_out;

  char* w = (char*)d_ws;
  auto alloc = [&](size_t bytes) {
    void* q = (void*)w; w += (bytes + 255) & ~(size_t)255; return q;
  };
  p.Xb    = (short*)alloc((size_t)2048 * 1024 * 2);  // X bf16
  p.Wvb   = (short*)alloc((size_t)256 * 1024 * 2);
  p.Wub   = (short*)alloc((size_t)256 * 1024 * 2);
  p.rmb   = (short*)alloc((size_t)1024 * 512 * 2);
  p.Wrb   = (short*)alloc((size_t)1024 * 512 * 2);
  p.Wo2b  = (short*)alloc((size_t)1024 * 512 * 2);
  p.swTb  = (short*)alloc((size_t)1024 * 1024 * 2);  // s_wT[h,r] bf16
  p.Ub    = (short*)alloc((size_t)1024 * 1024 * 2);  // U[h,r] bf16
  p.Weffb = (short*)alloc((size_t)1024 * 1024 * 2);  // Wo1 + U@s_wT^T bf16
  p.erb   = (short*)alloc((size_t)1024 * 1024 * 2);  // entity reprs bf16
  p.wpart = (float*)alloc((size_t)4 * 2048 * 4);     // gate partials
  p.cf    = (float*)alloc((size_t)1024 * 4);         // er . br
  p.gw2   = (float*)alloc((size_t)1024 * 4);         // rowsum(U)
  p.bar   = (unsigned*)alloc(256);                   // grid barrier state

  k0<<<512, 256, 0, stream>>>(p);   // convert + zero barrier words
  kF<<<512, 256, 0, stream>>>(p);   // phases 1-3 with in-kernel grid sync
}

// Round 6
// 156.740 us; speedup vs baseline: 2.3376x; 1.1122x over previous
//
#include <hip/hip_runtime.h>
#include <cstdint>
#include <cstddef>

#define NEG_ (-1e25f)

typedef __bf16 bf16x8 __attribute__((ext_vector_type(8)));
typedef float  f32x4  __attribute__((ext_vector_type(4)));
typedef short  s16x8  __attribute__((ext_vector_type(8)));
typedef const __attribute__((address_space(1))) void* gas_t;
typedef __attribute__((address_space(3))) void* las_t;

#define MFMA16 __builtin_amdgcn_mfma_f32_16x16x32_bf16

__device__ __forceinline__ short f2bf(float f) {
  union { float f; unsigned u; } v; v.f = f;
  unsigned r = v.u + 0x7fffu + ((v.u >> 16) & 1u);  // RNE
  return (short)(r >> 16);
}

__device__ __forceinline__ s16x8 cvt8(const float* s) {
  bf16x8 r;
  #pragma unroll
  for (int j = 0; j < 8; ++j) r[j] = (__bf16)s[j];  // fptrunc = RNE
  union { bf16x8 b; s16x8 s; } u; u.b = r; return u.s;
}

__device__ __forceinline__ void gload(const short* g, short* l) {
  __builtin_amdgcn_global_load_lds((gas_t)g, (las_t)l, 16, 0, 0);
}

struct Params {
  const float* ment; const int* ents; const int* msk;
  const float* rm; const float* Wv; const float* bv; const float* Wu;
  const float* bu; const float* Wa; const float* Wr; const float* br;
  const float* Wo; const float* bo; float* out;
  short *Xb, *Wvb, *Wub, *rmb, *Wrb, *Wo2b, *swTb, *Ub, *Weffb, *erb;
  float *wpart, *cf, *gw2;
};

// ================= k0: one-pass f32 -> bf16 conversion =================
__global__ __launch_bounds__(256) void k0(Params p) {
  const int g = blockIdx.x * 256 + threadIdx.x;
  #pragma unroll
  for (int it = 0; it < 4; ++it) {
    int u = g + it * 131072;
    long e = (long)u * 8;
    const float* src; short* dst;
    if (u < 262144)      { src = p.ment + e;                     dst = p.Xb + e; }
    else if (u < 294912) { long o = e - 2097152; src = p.Wv + o; dst = p.Wvb + o; }
    else if (u < 327680) { long o = e - 2359296; src = p.Wu + o; dst = p.Wub + o; }
    else if (u < 393216) { long o = e - 2621440; src = p.rm + o; dst = p.rmb + o; }
    else if (u < 458752) { long o = e - 3145728; src = p.Wr + o; dst = p.Wrb + o; }
    else                 { long o = e - 3670016;
                           src = p.Wo + (o >> 9) * 1536 + 1024 + (o & 511);
                           dst = p.Wo2b + o; }
    float t[8];
    *(float4*)t       = *(const float4*)src;
    *(float4*)(t + 4) = *(const float4*)(src + 4);
    *(s16x8*)dst = cvt8(t);
  }
}

// ======== m97-shape 128x128 GEMM, BK=32, 4 waves, 3-buf gload_lds ring ======
// Each wave: acc[4][4] (64x64 quadrant), 16 MFMA per 8 ds_read_b128 per K-step.
// EPI 0: C bf16 = acc.  EPI 1: C bf16 = acc + e0[row*1536+col] (Wo1).
// EPI 2: C f32 = acc + e0[col] + e1[row]*e2[col].
template <int NT, int EPI>
__device__ void mm128(const short* __restrict__ A, int lda,
                      const short* __restrict__ B, int ldb,
                      void* __restrict__ C, int ldc, int m0, int n0,
                      const float* __restrict__ e0, const float* __restrict__ e1,
                      const float* __restrict__ e2, short* lds) {
  short* As = lds;            // 3 bufs * 4096 shorts (128x32 tile)
  short* Bs = lds + 12288;
  const int tid = threadIdx.x, wave = tid >> 6, lane = tid & 63;
  const int quad = lane >> 4, l16 = lane & 15;
  const int wm = (wave & 1) * 64, wn = (wave >> 1) * 64;
  const int srow = tid >> 2, scol = (tid & 3) * 8;
  const short* Ag = A + (long)(m0 + srow) * lda + scol;
  const short* Bg = B + (long)(n0 + srow) * ldb + scol;
  const int wb = wave * 512;
  auto issue = [&](int kt) {
    int buf = kt % 3; int ko = kt * 32;
    gload(Ag + ko,            As + buf * 4096 + wb);
    gload(Ag + 64 * lda + ko, As + buf * 4096 + 2048 + wb);
    gload(Bg + ko,            Bs + buf * 4096 + wb);
    gload(Bg + 64 * ldb + ko, Bs + buf * 4096 + 2048 + wb);
  };
  f32x4 acc[4][4] = {};
  issue(0); issue(1);
  #pragma unroll
  for (int kt = 0; kt < NT; ++kt) {
    if (kt < NT - 1) asm volatile("s_waitcnt vmcnt(4)" ::: "memory");
    else             asm volatile("s_waitcnt vmcnt(0)" ::: "memory");
    asm volatile("s_barrier" ::: "memory");
    if (kt + 2 < NT) issue(kt + 2);
    const short* as = As + (kt % 3) * 4096;
    const short* bs = Bs + (kt % 3) * 4096;
    bf16x8 a[4], b[4];
    #pragma unroll
    for (int i = 0; i < 4; ++i)
      a[i] = *(const bf16x8*)&as[(wm + i * 16 + l16) * 32 + quad * 8];
    #pragma unroll
    for (int j = 0; j < 4; ++j)
      b[j] = *(const bf16x8*)&bs[(wn + j * 16 + l16) * 32 + quad * 8];
    #pragma unroll
    for (int i = 0; i < 4; ++i)
      #pragma unroll
      for (int j = 0; j < 4; ++j)
        acc[i][j] = MFMA16(a[i], b[j], acc[i][j], 0, 0, 0);
  }
  #pragma unroll
  for (int i = 0; i < 4; ++i)
    #pragma unroll
    for (int j = 0; j < 4; ++j) {
      int col = n0 + wn + j * 16 + l16;
      #pragma unroll
      for (int r = 0; r < 4; ++r) {
        int row = m0 + wm + i * 16 + quad * 4 + r;
        float v = acc[i][j][r];
        if constexpr (EPI == 0) {
          ((short*)C)[(long)row * ldc + col] = f2bf(v);
        } else if constexpr (EPI == 1) {
          v += e0[(long)row * 1536 + col];
          ((short*)C)[(long)row * ldc + col] = f2bf(v);
        } else {
          v += e0[col] + e1[row] * e2[col];
          ((float*)C)[(long)row * ldc + col] = v;
        }
      }
    }
}

// ==== vu gate: 128(M)x64(N) dual-B tile, same ring; fused gate epilogue ====
// logits_v = X@Wv^T, logits_u = X@Wu^T; wpart[ni][m] partial over 64 a-cols.
__device__ void mmvu(int q, const Params& p, short* lds, float* red) {
  short* As  = lds;                 // 3 bufs * 4096 (128x32)
  short* Bvs = lds + 12288;         // 3 bufs * 2048 (64x32)
  short* Bus = lds + 12288 + 6144;  // 3 bufs * 2048
  const int mi = q >> 2, ni = q & 3;
  const int m0 = mi * 128, n0 = ni * 64;
  const int tid = threadIdx.x, wave = tid >> 6, lane = tid & 63;
  const int quad = lane >> 4, l16 = lane & 15;
  const int wm = (wave & 1) * 64, wn = (wave >> 1) * 32;
  const int srow = tid >> 2, scol = (tid & 3) * 8;
  const short* Ag  = p.Xb  + (long)(m0 + srow) * 1024 + scol;
  const short* Bvg = p.Wvb + (long)(n0 + srow) * 1024 + scol;
  const short* Bug = p.Wub + (long)(n0 + srow) * 1024 + scol;
  const int wb = wave * 512;
  auto issue = [&](int kt) {
    int buf = kt % 3; int ko = kt * 32;
    gload(Ag + ko,             As + buf * 4096 + wb);
    gload(Ag + 64 * 1024 + ko, As + buf * 4096 + 2048 + wb);
    gload(Bvg + ko,            Bvs + buf * 2048 + wb);
    gload(Bug + ko,            Bus + buf * 2048 + wb);
  };
  f32x4 av[4][2] = {}, au[4][2] = {};
  issue(0); issue(1);
  #pragma unroll
  for (int kt = 0; kt < 32; ++kt) {
    if (kt < 31) asm volatile("s_waitcnt vmcnt(4)" ::: "memory");
    else         asm volatile("s_waitcnt vmcnt(0)" ::: "memory");
    asm volatile("s_barrier" ::: "memory");
    if (kt + 2 < 32) issue(kt + 2);
    const short* as  = As  + (kt % 3) * 4096;
    const short* bvs = Bvs + (kt % 3) * 2048;
    const short* bus = Bus + (kt % 3) * 2048;
    bf16x8 a[4], bv_[2], bu_[2];
    #pragma unroll
    for (int i = 0; i < 4; ++i)
      a[i] = *(const bf16x8*)&as[(wm + i * 16 + l16) * 32 + quad * 8];
    #pragma unroll
    for (int j = 0; j < 2; ++j) {
      bv_[j] = *(const bf16x8*)&bvs[(wn + j * 16 + l16) * 32 + quad * 8];
      bu_[j] = *(const bf16x8*)&bus[(wn + j * 16 + l16) * 32 + quad * 8];
    }
    #pragma unroll
    for (int i = 0; i < 4; ++i)
      #pragma unroll
      for (int j = 0; j < 2; ++j) {
        av[i][j] = MFMA16(a[i], bv_[j], av[i][j], 0, 0, 0);
        au[i][j] = MFMA16(a[i], bu_[j], au[i][j], 0, 0, 0);
      }
  }
  // gate epilogue: wsum[i][r] = sum over this wave's 32 a-cols
  float wsum[4][4];
  #pragma unroll
  for (int i = 0; i < 4; ++i)
    #pragma unroll
    for (int r = 0; r < 4; ++r) wsum[i][r] = 0.f;
  #pragma unroll
  for (int j = 0; j < 2; ++j) {
    int col = n0 + wn + j * 16 + l16;
    float bvc = p.bv[col], buc = p.bu[col], wac = p.Wa[col];
    #pragma unroll
    for (int i = 0; i < 4; ++i)
      #pragma unroll
      for (int r = 0; r < 4; ++r) {
        float vv = tanhf(av[i][j][r] + bvc);
        float uu = au[i][j][r] + buc;
        wsum[i][r] += (vv / (1.0f + expf(-uu))) * wac;
      }
  }
  #pragma unroll
  for (int i = 0; i < 4; ++i)
    #pragma unroll
    for (int r = 0; r < 4; ++r) {
      float s = wsum[i][r];
      s += __shfl_down(s, 8, 16);
      s += __shfl_down(s, 4, 16);
      s += __shfl_down(s, 2, 16);
      s += __shfl_down(s, 1, 16);
      if (l16 == 0) red[(wave >> 1) * 128 + wm + i * 16 + quad * 4 + r] = s;
    }
  __syncthreads();
  if (tid < 128) p.wpart[ni * 2048 + m0 + tid] = red[tid] + red[128 + tid];
}

// ---- gw2 rowsum, one row per wave ----
__device__ void gw2_wave(int row, const Params& p) {
  const int lane = threadIdx.x & 63;
  const short* u = p.Ub + (long)row * 1024 + lane * 16;
  union { s16x8 s; bf16x8 b; } w0, w1;
  w0.s = *(const s16x8*)u;
  w1.s = *(const s16x8*)(u + 8);
  float s = 0.f;
  #pragma unroll
  for (int j = 0; j < 8; ++j) s += (float)w0.b[j] + (float)w1.b[j];
  #pragma unroll
  for (int off = 32; off > 0; off >>= 1) s += __shfl_down(s, off);
  if (lane == 0) p.gw2[row] = s;
}

// ---- masked softmax over K=16 + pooling, ONE WAVE per entity (no LDS) ----
__device__ void entity_wave(int be, const Params& p) {
  const int lane = threadIdx.x & 63;
  const int b = be >> 7;  // E=128
  float a = NEG_; int idx = 0;
  if (lane < 16) {
    idx = p.ents[be * 16 + lane];
    int j = (b << 8) + idx;
    float lw = p.wpart[j] + p.wpart[2048 + j] + p.wpart[4096 + j] + p.wpart[6144 + j];
    a = p.msk[be * 16 + lane] ? lw : NEG_;
  }
  float m = a;
  m = fmaxf(m, __shfl_xor(m, 1, 16));
  m = fmaxf(m, __shfl_xor(m, 2, 16));
  m = fmaxf(m, __shfl_xor(m, 4, 16));
  m = fmaxf(m, __shfl_xor(m, 8, 16));
  float e = expf(a - m);
  float s = e;
  s += __shfl_xor(s, 1, 16);
  s += __shfl_xor(s, 2, 16);
  s += __shfl_xor(s, 4, 16);
  s += __shfl_xor(s, 8, 16);
  float aw = e / s;  // valid on lanes 0-15
  const float* Xr = p.ment + ((long)b << 18);
  const int h0 = lane * 16;
  float acc[16];
  #pragma unroll
  for (int t = 0; t < 16; ++t) acc[t] = 0.f;
  #pragma unroll
  for (int k = 0; k < 16; ++k) {
    float ak = __shfl(aw, k);
    int   ik = __shfl(idx, k);
    const float* xr = Xr + (long)ik * 1024 + h0;
    f32x4 x0 = *(const f32x4*)(xr);
    f32x4 x1 = *(const f32x4*)(xr + 4);
    f32x4 x2 = *(const f32x4*)(xr + 8);
    f32x4 x3 = *(const f32x4*)(xr + 12);
    #pragma unroll
    for (int t = 0; t < 4; ++t) {
      acc[t]      += ak * x0[t];
      acc[4 + t]  += ak * x1[t];
      acc[8 + t]  += ak * x2[t];
      acc[12 + t] += ak * x3[t];
    }
  }
  short* er = p.erb + (long)be * 1024 + h0;
  *(s16x8*)er       = cvt8(acc);
  *(s16x8*)(er + 8) = cvt8(acc + 8);
  float c = 0.f;
  const float* brp = p.br + h0;
  #pragma unroll
  for (int t = 0; t < 16; ++t) c += acc[t] * brp[t];
  #pragma unroll
  for (int off = 32; off > 0; off >>= 1) c += __shfl_down(c, off);
  if (lane == 0) p.cf[be] = c;
}

// ===== k1: vu gate (0-63) | s_wT = Wr@rm^T (64-127) | U = Wo2@rm^T (128-191)
__global__ __launch_bounds__(256) void k1(Params p) {
  __shared__ short lds[24576];   // 48 KB
  __shared__ float red[256];
  const int blk = blockIdx.x;
  if (blk < 64) {
    mmvu(blk, p, lds, red);
  } else if (blk < 128) {
    int q = blk - 64;
    mm128<16, 0>(p.Wrb, 512, p.rmb, 512, p.swTb, 1024,
                 (q >> 3) * 128, (q & 7) * 128, nullptr, nullptr, nullptr, lds);
  } else {
    int q = blk - 128;
    mm128<16, 0>(p.Wo2b, 512, p.rmb, 512, p.Ub, 1024,
                 (q >> 3) * 128, (q & 7) * 128, nullptr, nullptr, nullptr, lds);
  }
}

// ===== k2: Weff = Wo1 + U@s_wT^T (0-63) | gw2 + softmax (64-319) =====
__global__ __launch_bounds__(256) void k2(Params p) {
  __shared__ short lds[24576];
  const int blk = blockIdx.x;
  if (blk < 64) {
    mm128<32, 1>(p.Ub, 1024, p.swTb, 1024, p.Weffb, 1024,
                 (blk >> 3) * 128, (blk & 7) * 128, p.Wo, nullptr, nullptr, lds);
  } else {
    int q = blk - 64;
    int wave = threadIdx.x >> 6;
    gw2_wave(q * 4 + wave, p);
    entity_wave(q * 4 + wave, p);
  }
}

// ================= k3: out = er @ Weff^T + bo + cf*gw2 =================
__global__ __launch_bounds__(256) void k3(Params p) {
  __shared__ short lds[24576];
  const int blk = blockIdx.x;
  mm128<32, 2>(p.erb, 1024, p.Weffb, 1024, p.out, 1024,
               (blk >> 3) * 128, (blk & 7) * 128, p.bo, p.cf, p.gw2, lds);
}

extern "C" void kernel_launch(void* const* d_in, const int* in_sizes, int n_in,
                              void* d_out, int out_size, void* d_ws, size_t ws_size,
                              hipStream_t stream) {
  (void)in_sizes; (void)n_in; (void)out_size; (void)ws_size;
  Params p;
  p.ment = (const float*)d_in[0];
  p.ents = (const int*)d_in[1];
  p.msk  = (const int*)d_in[2];
  p.rm   = (const float*)d_in[3];
  p.Wv   = (const float*)d_in[4];
  p.bv   = (const float*)d_in[5];
  p.Wu   = (const float*)d_in[6];
  p.bu   = (const float*)d_in[7];
  p.Wa   = (const float*)d_in[8];
  // d_in[9] = ba: drops out (softmax shift-invariance)
  p.Wr   = (const float*)d_in[10];
  p.br   = (const float*)d_in[11];
  p.Wo   = (const float*)d_in[12];
  p.bo   = (const float*)d_in[13];
  p.out  = (float*)d_out;

  char* w = (char*)d_ws;
  auto alloc = [&](size_t bytes) {
    void* q = (void*)w; w += (bytes + 255) & ~(size_t)255; return q;
  };
  p.Xb    = (short*)alloc((size_t)2048 * 1024 * 2);  // X bf16
  p.Wvb   = (short*)alloc((size_t)256 * 1024 * 2);
  p.Wub   = (short*)alloc((size_t)256 * 1024 * 2);
  p.rmb   = (short*)alloc((size_t)1024 * 512 * 2);
  p.Wrb   = (short*)alloc((size_t)1024 * 512 * 2);
  p.Wo2b  = (short*)alloc((size_t)1024 * 512 * 2);
  p.swTb  = (short*)alloc((size_t)1024 * 1024 * 2);  // s_wT[h,r] bf16
  p.Ub    = (short*)alloc((size_t)1024 * 1024 * 2);  // U[h,r] bf16
  p.Weffb = (short*)alloc((size_t)1024 * 1024 * 2);  // Wo1 + U@s_wT^T bf16
  p.erb   = (short*)alloc((size_t)1024 * 1024 * 2);  // entity reprs bf16
  p.wpart = (float*)alloc((size_t)4 * 2048 * 4);     // gate partials
  p.cf    = (float*)alloc((size_t)1024 * 4);         // er . br
  p.gw2   = (float*)alloc((size_t)1024 * 4);         // rowsum(U)

  k0<<<512, 256, 0, stream>>>(p);
  k1<<<192, 256, 0, stream>>>(p);
  k2<<<320, 256, 0, stream>>>(p);
  k3<<<64, 256, 0, stream>>>(p);
}

// Round 7
// 135.721 us; speedup vs baseline: 2.6997x; 1.1549x over previous
//
#include <hip/hip_runtime.h>
#include <cstdint>
#include <cstddef>

#define NEG_ (-1e25f)

typedef __bf16 bf16x8 __attribute__((ext_vector_type(8)));
typedef float  f32x4  __attribute__((ext_vector_type(4)));
typedef short  s16x8  __attribute__((ext_vector_type(8)));
typedef const __attribute__((address_space(1))) void* gas_t;
typedef __attribute__((address_space(3))) void* las_t;

#define MFMA16 __builtin_amdgcn_mfma_f32_16x16x32_bf16

__device__ __forceinline__ short f2bf(float f) {
  union { float f; unsigned u; } v; v.f = f;
  unsigned r = v.u + 0x7fffu + ((v.u >> 16) & 1u);  // RNE
  return (short)(r >> 16);
}

__device__ __forceinline__ float bf2f(short s) {
  union { unsigned u; float f; } t; t.u = ((unsigned)(unsigned short)s) << 16;
  return t.f;
}

__device__ __forceinline__ s16x8 cvt8(const float* s) {
  bf16x8 r;
  #pragma unroll
  for (int j = 0; j < 8; ++j) r[j] = (__bf16)s[j];  // fptrunc = RNE
  union { bf16x8 b; s16x8 s; } u; u.b = r; return u.s;
}

__device__ __forceinline__ void gload(const short* g, short* l) {
  __builtin_amdgcn_global_load_lds((gas_t)g, (las_t)l, 16, 0, 0);
}

struct Params {
  const float* ment; const int* ents; const int* msk;
  const float* rm; const float* Wv; const float* bv; const float* Wu;
  const float* bu; const float* Wa; const float* Wr; const float* br;
  const float* Wo; const float* bo; float* out;
  short *Xb, *Wvb, *Wub, *rmb, *Wrb, *Wo2b, *Wo1b, *swTb, *Ub, *Weffb, *erb;
  float *wpart, *cf, *gw2;
};

// ====== k0: one-pass f32 -> bf16 of all GEMM operands (incl. Wo1) ======
// 5,242,880 floats = 655360 vec8 units; 131072 threads -> 5 units each.
__global__ __launch_bounds__(256) void k0(Params p) {
  const int g = blockIdx.x * 256 + threadIdx.x;
  #pragma unroll
  for (int it = 0; it < 5; ++it) {
    int u = g + it * 131072;
    long e = (long)u * 8;
    const float* src; short* dst;
    if (u < 262144)      { src = p.ment + e;                     dst = p.Xb + e; }
    else if (u < 294912) { long o = e - 2097152; src = p.Wv + o; dst = p.Wvb + o; }
    else if (u < 327680) { long o = e - 2359296; src = p.Wu + o; dst = p.Wub + o; }
    else if (u < 393216) { long o = e - 2621440; src = p.rm + o; dst = p.rmb + o; }
    else if (u < 458752) { long o = e - 3145728; src = p.Wr + o; dst = p.Wrb + o; }
    else if (u < 524288) { long o = e - 3670016;
                           src = p.Wo + (o >> 9) * 1536 + 1024 + (o & 511);
                           dst = p.Wo2b + o; }
    else                 { long o = e - 4194304;
                           src = p.Wo + (o >> 10) * 1536 + (o & 1023);
                           dst = p.Wo1b + o; }
    float t[8];
    *(float4*)t       = *(const float4*)src;
    *(float4*)(t + 4) = *(const float4*)(src + 4);
    *(s16x8*)dst = cvt8(t);
  }
}

// ====== 64x64 bf16 GEMM, DEEP ring: 8 bufs, prefetch depth 6 ======
// 2 gload_lds per wave per iter -> 12 outstanding in steady state.
// EPI 0: C bf16 = acc.  EPI 1: C bf16 = acc + bf2f(w1[row*1024+col]).
// EPI 2: C f32 = acc + e0[col] + e1[row]*e2[col].
template <int NT, int EPI>
__device__ void g64(const short* __restrict__ A, int lda,
                    const short* __restrict__ B, int ldb,
                    void* __restrict__ C, int ldc, int m0, int n0,
                    const short* __restrict__ w1, const float* __restrict__ e0,
                    const float* __restrict__ e1, const float* __restrict__ e2,
                    short* lds) {
  short* As = lds;            // 8 bufs * 2048 shorts (64x32)
  short* Bs = lds + 16384;
  const int tid = threadIdx.x, wave = tid >> 6, lane = tid & 63;
  const int quad = lane >> 4, l16 = lane & 15;
  const int wm = (wave & 1) * 32, wn = (wave >> 1) * 32;
  const int srow = tid >> 2, scol = (tid & 3) * 8;
  const short* Ag = A + (long)(m0 + srow) * lda + scol;
  const short* Bg = B + (long)(n0 + srow) * ldb + scol;
  const int wb = wave * 512;
  auto issue = [&](int kt) {
    int buf = kt & 7; int ko = kt * 32;
    gload(Ag + ko, As + buf * 2048 + wb);
    gload(Bg + ko, Bs + buf * 2048 + wb);
  };
  f32x4 acc[2][2] = {};
  issue(0); issue(1); issue(2); issue(3); issue(4); issue(5);
  for (int kt = 0; kt < NT; ++kt) {
    int rem = NT - 1 - kt;
    if (rem >= 5)      asm volatile("s_waitcnt vmcnt(10)" ::: "memory");
    else if (rem == 4) asm volatile("s_waitcnt vmcnt(8)" ::: "memory");
    else if (rem == 3) asm volatile("s_waitcnt vmcnt(6)" ::: "memory");
    else if (rem == 2) asm volatile("s_waitcnt vmcnt(4)" ::: "memory");
    else if (rem == 1) asm volatile("s_waitcnt vmcnt(2)" ::: "memory");
    else               asm volatile("s_waitcnt vmcnt(0)" ::: "memory");
    asm volatile("s_barrier" ::: "memory");
    if (kt + 6 < NT) issue(kt + 6);
    const short* as = As + (kt & 7) * 2048;
    const short* bs = Bs + (kt & 7) * 2048;
    bf16x8 a0 = *(const bf16x8*)&as[(wm + l16) * 32 + quad * 8];
    bf16x8 a1 = *(const bf16x8*)&as[(wm + 16 + l16) * 32 + quad * 8];
    bf16x8 b0 = *(const bf16x8*)&bs[(wn + l16) * 32 + quad * 8];
    bf16x8 b1 = *(const bf16x8*)&bs[(wn + 16 + l16) * 32 + quad * 8];
    acc[0][0] = MFMA16(a0, b0, acc[0][0], 0, 0, 0);
    acc[0][1] = MFMA16(a0, b1, acc[0][1], 0, 0, 0);
    acc[1][0] = MFMA16(a1, b0, acc[1][0], 0, 0, 0);
    acc[1][1] = MFMA16(a1, b1, acc[1][1], 0, 0, 0);
  }
  #pragma unroll
  for (int i = 0; i < 2; ++i)
    #pragma unroll
    for (int j = 0; j < 2; ++j) {
      int col = n0 + wn + j * 16 + l16;
      #pragma unroll
      for (int r = 0; r < 4; ++r) {
        int row = m0 + wm + i * 16 + quad * 4 + r;
        float v = acc[i][j][r];
        if constexpr (EPI == 0) {
          ((short*)C)[(long)row * ldc + col] = f2bf(v);
        } else if constexpr (EPI == 1) {
          v += bf2f(w1[(long)row * 1024 + col]);
          ((short*)C)[(long)row * ldc + col] = f2bf(v);
        } else {
          v += e0[col] + e1[row] * e2[col];
          ((float*)C)[(long)row * ldc + col] = v;
        }
      }
    }
}

// ====== vu gate 32(M)x64(N), deep ring: 6 bufs, prefetch depth 4 ======
// waves 0-1: 3 loads/iter; waves 2-3: 2 loads/iter.
__device__ void vu_ring(int mi, int ni, const Params& p, short* lds, float* red) {
  short* As  = lds;                        // 6 bufs * 1024 shorts (32x32)
  short* Bvs = lds + 6 * 1024;             // 6 bufs * 2048 (64x32)
  short* Bus = lds + 6 * 1024 + 6 * 2048;  // 6 bufs * 2048
  const int tid = threadIdx.x, wave = tid >> 6, lane = tid & 63;
  const int quad = lane >> 4, l16 = lane & 15;
  const int wm = (wave & 1) * 16, wn = (wave >> 1) * 32;
  const int m0 = mi * 32, n0 = ni * 64;
  const int srow = tid >> 2, scol = (tid & 3) * 8;
  const short* Ag  = p.Xb  + (long)(m0 + srow) * 1024 + scol;  // waves 0-1 only
  const short* Bvg = p.Wvb + (long)(n0 + srow) * 1024 + scol;
  const short* Bug = p.Wub + (long)(n0 + srow) * 1024 + scol;
  const int wb = wave * 512;
  auto issue = [&](int kt) {
    int buf = kt % 6; int ko = kt * 32;
    if (wave < 2)
      gload(Ag + ko, As + buf * 1024 + wb);
    gload(Bvg + ko, Bvs + buf * 2048 + wb);
    gload(Bug + ko, Bus + buf * 2048 + wb);
  };
  f32x4 accv[2] = {}, accu[2] = {};
  issue(0); issue(1); issue(2); issue(3);
  for (int kt = 0; kt < 32; ++kt) {
    int rem = 31 - kt;
    if (wave < 2) {  // 3 loads/iter
      if (rem >= 3)      asm volatile("s_waitcnt vmcnt(9)" ::: "memory");
      else if (rem == 2) asm volatile("s_waitcnt vmcnt(6)" ::: "memory");
      else if (rem == 1) asm volatile("s_waitcnt vmcnt(3)" ::: "memory");
      else               asm volatile("s_waitcnt vmcnt(0)" ::: "memory");
    } else {         // 2 loads/iter
      if (rem >= 3)      asm volatile("s_waitcnt vmcnt(6)" ::: "memory");
      else if (rem == 2) asm volatile("s_waitcnt vmcnt(4)" ::: "memory");
      else if (rem == 1) asm volatile("s_waitcnt vmcnt(2)" ::: "memory");
      else               asm volatile("s_waitcnt vmcnt(0)" ::: "memory");
    }
    asm volatile("s_barrier" ::: "memory");
    if (kt + 4 < 32) issue(kt + 4);
    const short* as  = As  + (kt % 6) * 1024;
    const short* bvs = Bvs + (kt % 6) * 2048;
    const short* bus = Bus + (kt % 6) * 2048;
    bf16x8 af = *(const bf16x8*)&as[(wm + l16) * 32 + quad * 8];
    bf16x8 v0 = *(const bf16x8*)&bvs[(wn + l16) * 32 + quad * 8];
    bf16x8 v1 = *(const bf16x8*)&bvs[(wn + 16 + l16) * 32 + quad * 8];
    bf16x8 u0 = *(const bf16x8*)&bus[(wn + l16) * 32 + quad * 8];
    bf16x8 u1 = *(const bf16x8*)&bus[(wn + 16 + l16) * 32 + quad * 8];
    accv[0] = MFMA16(af, v0, accv[0], 0, 0, 0);
    accv[1] = MFMA16(af, v1, accv[1], 0, 0, 0);
    accu[0] = MFMA16(af, u0, accu[0], 0, 0, 0);
    accu[1] = MFMA16(af, u1, accu[1], 0, 0, 0);
  }
  float wsum[4] = {0.f, 0.f, 0.f, 0.f};
  #pragma unroll
  for (int j = 0; j < 2; ++j) {
    int col = n0 + wn + j * 16 + l16;
    float bvc = p.bv[col], buc = p.bu[col], wac = p.Wa[col];
    #pragma unroll
    for (int r = 0; r < 4; ++r) {
      float vv = tanhf(accv[j][r] + bvc);
      float uu = accu[j][r] + buc;
      wsum[r] += (vv / (1.0f + expf(-uu))) * wac;
    }
  }
  #pragma unroll
  for (int r = 0; r < 4; ++r) {
    float s = wsum[r];
    s += __shfl_down(s, 8, 16);
    s += __shfl_down(s, 4, 16);
    s += __shfl_down(s, 2, 16);
    s += __shfl_down(s, 1, 16);
    if (l16 == 0) red[(wave >> 1) * 32 + wm + quad * 4 + r] = s;
  }
  __syncthreads();
  if (tid < 32) p.wpart[ni * 2048 + m0 + tid] = red[tid] + red[32 + tid];
}

// ---- gw2 rowsum, one row per wave ----
__device__ void gw2_wave(int row, const Params& p) {
  const int lane = threadIdx.x & 63;
  const short* u = p.Ub + (long)row * 1024 + lane * 16;
  union { s16x8 s; bf16x8 b; } w0, w1;
  w0.s = *(const s16x8*)u;
  w1.s = *(const s16x8*)(u + 8);
  float s = 0.f;
  #pragma unroll
  for (int j = 0; j < 8; ++j) s += (float)w0.b[j] + (float)w1.b[j];
  #pragma unroll
  for (int off = 32; off > 0; off >>= 1) s += __shfl_down(s, off);
  if (lane == 0) p.gw2[row] = s;
}

// ---- masked softmax over K=16 + pooling, ONE WAVE per entity (no LDS) ----
__device__ void entity_wave(int be, const Params& p) {
  const int lane = threadIdx.x & 63;
  const int b = be >> 7;  // E=128
  float a = NEG_; int idx = 0;
  if (lane < 16) {
    idx = p.ents[be * 16 + lane];
    int j = (b << 8) + idx;
    float lw = p.wpart[j] + p.wpart[2048 + j] + p.wpart[4096 + j] + p.wpart[6144 + j];
    a = p.msk[be * 16 + lane] ? lw : NEG_;
  }
  float m = a;
  m = fmaxf(m, __shfl_xor(m, 1, 16));
  m = fmaxf(m, __shfl_xor(m, 2, 16));
  m = fmaxf(m, __shfl_xor(m, 4, 16));
  m = fmaxf(m, __shfl_xor(m, 8, 16));
  float e = expf(a - m);
  float s = e;
  s += __shfl_xor(s, 1, 16);
  s += __shfl_xor(s, 2, 16);
  s += __shfl_xor(s, 4, 16);
  s += __shfl_xor(s, 8, 16);
  float aw = e / s;  // valid on lanes 0-15
  const float* Xr = p.ment + ((long)b << 18);
  const int h0 = lane * 16;
  float acc[16];
  #pragma unroll
  for (int t = 0; t < 16; ++t) acc[t] = 0.f;
  #pragma unroll
  for (int k = 0; k < 16; ++k) {
    float ak = __shfl(aw, k);
    int   ik = __shfl(idx, k);
    const float* xr = Xr + (long)ik * 1024 + h0;
    f32x4 x0 = *(const f32x4*)(xr);
    f32x4 x1 = *(const f32x4*)(xr + 4);
    f32x4 x2 = *(const f32x4*)(xr + 8);
    f32x4 x3 = *(const f32x4*)(xr + 12);
    #pragma unroll
    for (int t = 0; t < 4; ++t) {
      acc[t]      += ak * x0[t];
      acc[4 + t]  += ak * x1[t];
      acc[8 + t]  += ak * x2[t];
      acc[12 + t] += ak * x3[t];
    }
  }
  short* er = p.erb + (long)be * 1024 + h0;
  *(s16x8*)er       = cvt8(acc);
  *(s16x8*)(er + 8) = cvt8(acc + 8);
  float c = 0.f;
  const float* brp = p.br + h0;
  #pragma unroll
  for (int t = 0; t < 16; ++t) c += acc[t] * brp[t];
  #pragma unroll
  for (int off = 32; off > 0; off >>= 1) c += __shfl_down(c, off);
  if (lane == 0) p.cf[be] = c;
}

// == k1: vu gate (0-255) | s_wT = Wr@rm^T (256-511) | U = Wo2@rm^T (512-767) ==
__global__ __launch_bounds__(256) void k1(Params p) {
  __shared__ short lds[32768];   // 64 KB
  __shared__ float red[64];
  const int blk = blockIdx.x;
  if (blk < 256) {
    vu_ring(blk & 63, blk >> 6, p, lds, red);
  } else if (blk < 512) {
    int q = blk - 256;
    g64<16, 0>(p.Wrb, 512, p.rmb, 512, p.swTb, 1024,
               (q >> 4) * 64, (q & 15) * 64, nullptr, nullptr, nullptr, nullptr, lds);
  } else {
    int q = blk - 512;
    g64<16, 0>(p.Wo2b, 512, p.rmb, 512, p.Ub, 1024,
               (q >> 4) * 64, (q & 15) * 64, nullptr, nullptr, nullptr, nullptr, lds);
  }
}

// ==== k2: Weff = Wo1 + U@s_wT^T (0-255) | gw2 + softmax (256-511) ====
__global__ __launch_bounds__(256) void k2(Params p) {
  __shared__ short lds[32768];
  const int blk = blockIdx.x;
  if (blk < 256) {
    g64<32, 1>(p.Ub, 1024, p.swTb, 1024, p.Weffb, 1024,
               (blk >> 4) * 64, (blk & 15) * 64, p.Wo1b, nullptr, nullptr, nullptr, lds);
  } else {
    int q = blk - 256;
    int wave = threadIdx.x >> 6;
    gw2_wave(q * 4 + wave, p);
    entity_wave(q * 4 + wave, p);
  }
}

// ================= k3: out = er @ Weff^T + bo + cf*gw2 =================
__global__ __launch_bounds__(256) void k3(Params p) {
  __shared__ short lds[32768];
  const int blk = blockIdx.x;
  g64<32, 2>(p.erb, 1024, p.Weffb, 1024, p.out, 1024,
             (blk >> 4) * 64, (blk & 15) * 64, nullptr, p.bo, p.cf, p.gw2, lds);
}

extern "C" void kernel_launch(void* const* d_in, const int* in_sizes, int n_in,
                              void* d_out, int out_size, void* d_ws, size_t ws_size,
                              hipStream_t stream) {
  (void)in_sizes; (void)n_in; (void)out_size; (void)ws_size;
  Params p;
  p.ment = (const float*)d_in[0];
  p.ents = (const int*)d_in[1];
  p.msk  = (const int*)d_in[2];
  p.rm   = (const float*)d_in[3];
  p.Wv   = (const float*)d_in[4];
  p.bv   = (const float*)d_in[5];
  p.Wu   = (const float*)d_in[6];
  p.bu   = (const float*)d_in[7];
  p.Wa   = (const float*)d_in[8];
  // d_in[9] = ba: drops out (softmax shift-invariance)
  p.Wr   = (const float*)d_in[10];
  p.br   = (const float*)d_in[11];
  p.Wo   = (const float*)d_in[12];
  p.bo   = (const float*)d_in[13];
  p.out  = (float*)d_out;

  char* w = (char*)d_ws;
  auto alloc = [&](size_t bytes) {
    void* q = (void*)w; w += (bytes + 255) & ~(size_t)255; return q;
  };
  p.Xb    = (short*)alloc((size_t)2048 * 1024 * 2);  // X bf16
  p.Wvb   = (short*)alloc((size_t)256 * 1024 * 2);
  p.Wub   = (short*)alloc((size_t)256 * 1024 * 2);
  p.rmb   = (short*)alloc((size_t)1024 * 512 * 2);
  p.Wrb   = (short*)alloc((size_t)1024 * 512 * 2);
  p.Wo2b  = (short*)alloc((size_t)1024 * 512 * 2);
  p.Wo1b  = (short*)alloc((size_t)1024 * 1024 * 2);  // Wo1 bf16 (dense 1024x1024)
  p.swTb  = (short*)alloc((size_t)1024 * 1024 * 2);  // s_wT[h,r] bf16
  p.Ub    = (short*)alloc((size_t)1024 * 1024 * 2);  // U[h,r] bf16
  p.Weffb = (short*)alloc((size_t)1024 * 1024 * 2);  // Wo1 + U@s_wT^T bf16
  p.erb   = (short*)alloc((size_t)1024 * 1024 * 2);  // entity reprs bf16
  p.wpart = (float*)alloc((size_t)4 * 2048 * 4);     // gate partials
  p.cf    = (float*)alloc((size_t)1024 * 4);         // er . br
  p.gw2   = (float*)alloc((size_t)1024 * 4);         // rowsum(U)

  k0<<<512, 256, 0, stream>>>(p);
  k1<<<768, 256, 0, stream>>>(p);
  k2<<<512, 256, 0, stream>>>(p);
  k3<<<256, 256, 0, stream>>>(p);
}

// Round 8
// 130.978 us; speedup vs baseline: 2.7974x; 1.0362x over previous
//
#include <hip/hip_runtime.h>
#include <cstdint>
#include <cstddef>

#define NEG_ (-1e25f)

typedef __bf16 bf16x8 __attribute__((ext_vector_type(8)));
typedef float  f32x4  __attribute__((ext_vector_type(4)));
typedef short  s16x8  __attribute__((ext_vector_type(8)));
typedef const __attribute__((address_space(1))) void* gas_t;
typedef __attribute__((address_space(3))) void* las_t;

#define MFMA16 __builtin_amdgcn_mfma_f32_16x16x32_bf16

__device__ __forceinline__ short f2bf(float f) {
  union { float f; unsigned u; } v; v.f = f;
  unsigned r = v.u + 0x7fffu + ((v.u >> 16) & 1u);  // RNE
  return (short)(r >> 16);
}

__device__ __forceinline__ float bf2f(short s) {
  union { unsigned u; float f; } t; t.u = ((unsigned)(unsigned short)s) << 16;
  return t.f;
}

__device__ __forceinline__ s16x8 cvt8(const float* s) {
  bf16x8 r;
  #pragma unroll
  for (int j = 0; j < 8; ++j) r[j] = (__bf16)s[j];  // fptrunc = RNE
  union { bf16x8 b; s16x8 s; } u; u.b = r; return u.s;
}

__device__ __forceinline__ void gload(const short* g, short* l) {
  __builtin_amdgcn_global_load_lds((gas_t)g, (las_t)l, 16, 0, 0);
}

struct Params {
  const float* ment; const int* ents; const int* msk;
  const float* rm; const float* Wv; const float* bv; const float* Wu;
  const float* bu; const float* Wa; const float* Wr; const float* br;
  const float* Wo; const float* bo; float* out;
  short *Xb, *Wvb, *Wub, *rmb, *Wrb, *Wo2b, *Wo1b, *swTb, *Ub, *Weffb, *erb;
  float *wpart, *cf, *gw2;
};

// ====== k0: one-pass f32 -> bf16 (X, Wv, Wu, rm, Wr, Wo2; Wo1 moved to k1) ==
// 4,194,304 floats = 524288 vec8 units; 131072 threads -> 4 units each.
__global__ __launch_bounds__(256) void k0(Params p) {
  const int g = blockIdx.x * 256 + threadIdx.x;
  #pragma unroll
  for (int it = 0; it < 4; ++it) {
    int u = g + it * 131072;
    long e = (long)u * 8;
    const float* src; short* dst;
    if (u < 262144)      { src = p.ment + e;                     dst = p.Xb + e; }
    else if (u < 294912) { long o = e - 2097152; src = p.Wv + o; dst = p.Wvb + o; }
    else if (u < 327680) { long o = e - 2359296; src = p.Wu + o; dst = p.Wub + o; }
    else if (u < 393216) { long o = e - 2621440; src = p.rm + o; dst = p.rmb + o; }
    else if (u < 458752) { long o = e - 3145728; src = p.Wr + o; dst = p.Wrb + o; }
    else                 { long o = e - 3670016;
                           src = p.Wo + (o >> 9) * 1536 + 1024 + (o & 511);
                           dst = p.Wo2b + o; }
    float t[8];
    *(float4*)t       = *(const float4*)src;
    *(float4*)(t + 4) = *(const float4*)(src + 4);
    *(s16x8*)dst = cvt8(t);
  }
}

// ====== 64x64 bf16 GEMM, DEEP ring: 8 bufs, prefetch depth 6 ======
template <int NT, int EPI>
__device__ void g64(const short* __restrict__ A, int lda,
                    const short* __restrict__ B, int ldb,
                    void* __restrict__ C, int ldc, int m0, int n0,
                    const short* __restrict__ w1, const float* __restrict__ e0,
                    const float* __restrict__ e1, const float* __restrict__ e2,
                    short* lds) {
  short* As = lds;            // 8 bufs * 2048 shorts (64x32)
  short* Bs = lds + 16384;
  const int tid = threadIdx.x, wave = tid >> 6, lane = tid & 63;
  const int quad = lane >> 4, l16 = lane & 15;
  const int wm = (wave & 1) * 32, wn = (wave >> 1) * 32;
  const int srow = tid >> 2, scol = (tid & 3) * 8;
  const short* Ag = A + (long)(m0 + srow) * lda + scol;
  const short* Bg = B + (long)(n0 + srow) * ldb + scol;
  const int wb = wave * 512;
  auto issue = [&](int kt) {
    int buf = kt & 7; int ko = kt * 32;
    gload(Ag + ko, As + buf * 2048 + wb);
    gload(Bg + ko, Bs + buf * 2048 + wb);
  };
  f32x4 acc[2][2] = {};
  issue(0); issue(1); issue(2); issue(3); issue(4); issue(5);
  for (int kt = 0; kt < NT; ++kt) {
    int rem = NT - 1 - kt;
    if (rem >= 5)      asm volatile("s_waitcnt vmcnt(10)" ::: "memory");
    else if (rem == 4) asm volatile("s_waitcnt vmcnt(8)" ::: "memory");
    else if (rem == 3) asm volatile("s_waitcnt vmcnt(6)" ::: "memory");
    else if (rem == 2) asm volatile("s_waitcnt vmcnt(4)" ::: "memory");
    else if (rem == 1) asm volatile("s_waitcnt vmcnt(2)" ::: "memory");
    else               asm volatile("s_waitcnt vmcnt(0)" ::: "memory");
    asm volatile("s_barrier" ::: "memory");
    if (kt + 6 < NT) issue(kt + 6);
    const short* as = As + (kt & 7) * 2048;
    const short* bs = Bs + (kt & 7) * 2048;
    bf16x8 a0 = *(const bf16x8*)&as[(wm + l16) * 32 + quad * 8];
    bf16x8 a1 = *(const bf16x8*)&as[(wm + 16 + l16) * 32 + quad * 8];
    bf16x8 b0 = *(const bf16x8*)&bs[(wn + l16) * 32 + quad * 8];
    bf16x8 b1 = *(const bf16x8*)&bs[(wn + 16 + l16) * 32 + quad * 8];
    acc[0][0] = MFMA16(a0, b0, acc[0][0], 0, 0, 0);
    acc[0][1] = MFMA16(a0, b1, acc[0][1], 0, 0, 0);
    acc[1][0] = MFMA16(a1, b0, acc[1][0], 0, 0, 0);
    acc[1][1] = MFMA16(a1, b1, acc[1][1], 0, 0, 0);
  }
  #pragma unroll
  for (int i = 0; i < 2; ++i)
    #pragma unroll
    for (int j = 0; j < 2; ++j) {
      int col = n0 + wn + j * 16 + l16;
      #pragma unroll
      for (int r = 0; r < 4; ++r) {
        int row = m0 + wm + i * 16 + quad * 4 + r;
        float v = acc[i][j][r];
        if constexpr (EPI == 0) {
          ((short*)C)[(long)row * ldc + col] = f2bf(v);
        } else if constexpr (EPI == 1) {
          v += bf2f(w1[(long)row * 1024 + col]);
          ((short*)C)[(long)row * ldc + col] = f2bf(v);
        } else {
          v += e0[col] + e1[row] * e2[col];
          ((float*)C)[(long)row * ldc + col] = v;
        }
      }
    }
}

// ====== vu gate 32(M)x64(N), deep ring: 6 bufs, prefetch depth 4 ======
__device__ void vu_ring(int mi, int ni, const Params& p, short* lds, float* red) {
  short* As  = lds;                        // 6 bufs * 1024 shorts (32x32)
  short* Bvs = lds + 6 * 1024;             // 6 bufs * 2048 (64x32)
  short* Bus = lds + 6 * 1024 + 6 * 2048;  // 6 bufs * 2048
  const int tid = threadIdx.x, wave = tid >> 6, lane = tid & 63;
  const int quad = lane >> 4, l16 = lane & 15;
  const int wm = (wave & 1) * 16, wn = (wave >> 1) * 32;
  const int m0 = mi * 32, n0 = ni * 64;
  const int srow = tid >> 2, scol = (tid & 3) * 8;
  const short* Ag  = p.Xb  + (long)(m0 + srow) * 1024 + scol;  // waves 0-1 only
  const short* Bvg = p.Wvb + (long)(n0 + srow) * 1024 + scol;
  const short* Bug = p.Wub + (long)(n0 + srow) * 1024 + scol;
  const int wb = wave * 512;
  auto issue = [&](int kt) {
    int buf = kt % 6; int ko = kt * 32;
    if (wave < 2)
      gload(Ag + ko, As + buf * 1024 + wb);
    gload(Bvg + ko, Bvs + buf * 2048 + wb);
    gload(Bug + ko, Bus + buf * 2048 + wb);
  };
  f32x4 accv[2] = {}, accu[2] = {};
  issue(0); issue(1); issue(2); issue(3);
  for (int kt = 0; kt < 32; ++kt) {
    int rem = 31 - kt;
    if (wave < 2) {  // 3 loads/iter
      if (rem >= 3)      asm volatile("s_waitcnt vmcnt(9)" ::: "memory");
      else if (rem == 2) asm volatile("s_waitcnt vmcnt(6)" ::: "memory");
      else if (rem == 1) asm volatile("s_waitcnt vmcnt(3)" ::: "memory");
      else               asm volatile("s_waitcnt vmcnt(0)" ::: "memory");
    } else {         // 2 loads/iter
      if (rem >= 3)      asm volatile("s_waitcnt vmcnt(6)" ::: "memory");
      else if (rem == 2) asm volatile("s_waitcnt vmcnt(4)" ::: "memory");
      else if (rem == 1) asm volatile("s_waitcnt vmcnt(2)" ::: "memory");
      else               asm volatile("s_waitcnt vmcnt(0)" ::: "memory");
    }
    asm volatile("s_barrier" ::: "memory");
    if (kt + 4 < 32) issue(kt + 4);
    const short* as  = As  + (kt % 6) * 1024;
    const short* bvs = Bvs + (kt % 6) * 2048;
    const short* bus = Bus + (kt % 6) * 2048;
    bf16x8 af = *(const bf16x8*)&as[(wm + l16) * 32 + quad * 8];
    bf16x8 v0 = *(const bf16x8*)&bvs[(wn + l16) * 32 + quad * 8];
    bf16x8 v1 = *(const bf16x8*)&bvs[(wn + 16 + l16) * 32 + quad * 8];
    bf16x8 u0 = *(const bf16x8*)&bus[(wn + l16) * 32 + quad * 8];
    bf16x8 u1 = *(const bf16x8*)&bus[(wn + 16 + l16) * 32 + quad * 8];
    accv[0] = MFMA16(af, v0, accv[0], 0, 0, 0);
    accv[1] = MFMA16(af, v1, accv[1], 0, 0, 0);
    accu[0] = MFMA16(af, u0, accu[0], 0, 0, 0);
    accu[1] = MFMA16(af, u1, accu[1], 0, 0, 0);
  }
  float wsum[4] = {0.f, 0.f, 0.f, 0.f};
  #pragma unroll
  for (int j = 0; j < 2; ++j) {
    int col = n0 + wn + j * 16 + l16;
    float bvc = p.bv[col], buc = p.bu[col], wac = p.Wa[col];
    #pragma unroll
    for (int r = 0; r < 4; ++r) {
      float vv = tanhf(accv[j][r] + bvc);
      float uu = accu[j][r] + buc;
      wsum[r] += (vv / (1.0f + expf(-uu))) * wac;
    }
  }
  #pragma unroll
  for (int r = 0; r < 4; ++r) {
    float s = wsum[r];
    s += __shfl_down(s, 8, 16);
    s += __shfl_down(s, 4, 16);
    s += __shfl_down(s, 2, 16);
    s += __shfl_down(s, 1, 16);
    if (l16 == 0) red[(wave >> 1) * 32 + wm + quad * 4 + r] = s;
  }
  __syncthreads();
  if (tid < 32) p.wpart[ni * 2048 + m0 + tid] = red[tid] + red[32 + tid];
}

// ---- gw2 rowsum, one row per wave ----
__device__ void gw2_wave(int row, const Params& p) {
  const int lane = threadIdx.x & 63;
  const short* u = p.Ub + (long)row * 1024 + lane * 16;
  union { s16x8 s; bf16x8 b; } w0, w1;
  w0.s = *(const s16x8*)u;
  w1.s = *(const s16x8*)(u + 8);
  float s = 0.f;
  #pragma unroll
  for (int j = 0; j < 8; ++j) s += (float)w0.b[j] + (float)w1.b[j];
  #pragma unroll
  for (int off = 32; off > 0; off >>= 1) s += __shfl_down(s, off);
  if (lane == 0) p.gw2[row] = s;
}

// ---- masked softmax K=16 + pooling, ONE WAVE per entity, bf16 X gather ----
// Gathers from Xb (bf16): half the line volume of f32 ment; loads batched
// 8 rows deep (16 outstanding 16B loads) for MLP instead of serial chain.
__device__ void entity_wave(int be, const Params& p) {
  const int lane = threadIdx.x & 63;
  const int b = be >> 7;  // E=128
  float a = NEG_; int idx = 0;
  if (lane < 16) {
    idx = p.ents[be * 16 + lane];
    int j = (b << 8) + idx;
    float lw = p.wpart[j] + p.wpart[2048 + j] + p.wpart[4096 + j] + p.wpart[6144 + j];
    a = p.msk[be * 16 + lane] ? lw : NEG_;
  }
  float m = a;
  m = fmaxf(m, __shfl_xor(m, 1, 16));
  m = fmaxf(m, __shfl_xor(m, 2, 16));
  m = fmaxf(m, __shfl_xor(m, 4, 16));
  m = fmaxf(m, __shfl_xor(m, 8, 16));
  float e = expf(a - m);
  float s = e;
  s += __shfl_xor(s, 1, 16);
  s += __shfl_xor(s, 2, 16);
  s += __shfl_xor(s, 4, 16);
  s += __shfl_xor(s, 8, 16);
  float aw = e / s;  // valid on lanes 0-15
  // hoist all (a_k, idx_k) first — removes the shuffle from the load loop
  float ak[16]; int ik[16];
  #pragma unroll
  for (int k = 0; k < 16; ++k) { ak[k] = __shfl(aw, k); ik[k] = __shfl(idx, k); }
  const short* Xr = p.Xb + ((long)b << 18);  // 256*1024 bf16 per batch
  const int h0 = lane * 16;
  float acc[16];
  #pragma unroll
  for (int t = 0; t < 16; ++t) acc[t] = 0.f;
  #pragma unroll
  for (int c = 0; c < 2; ++c) {
    s16x8 xv[8][2];
    #pragma unroll
    for (int k = 0; k < 8; ++k) {          // 16 loads issued back-to-back
      const short* xr = Xr + (long)ik[c * 8 + k] * 1024 + h0;
      xv[k][0] = *(const s16x8*)xr;
      xv[k][1] = *(const s16x8*)(xr + 8);
    }
    #pragma unroll
    for (int k = 0; k < 8; ++k) {
      union { s16x8 s; bf16x8 b; } u0, u1;
      u0.s = xv[k][0]; u1.s = xv[k][1];
      float akk = ak[c * 8 + k];
      #pragma unroll
      for (int t = 0; t < 8; ++t) {
        acc[t]     += akk * (float)u0.b[t];
        acc[8 + t] += akk * (float)u1.b[t];
      }
    }
  }
  short* er = p.erb + (long)be * 1024 + h0;
  *(s16x8*)er       = cvt8(acc);
  *(s16x8*)(er + 8) = cvt8(acc + 8);
  float c = 0.f;
  const float* brp = p.br + h0;
  #pragma unroll
  for (int t = 0; t < 16; ++t) c += acc[t] * brp[t];
  #pragma unroll
  for (int off = 32; off > 0; off >>= 1) c += __shfl_down(c, off);
  if (lane == 0) p.cf[be] = c;
}

// == k1: vu gate (0-255) | s_wT (256-511) | U (512-767) | Wo1 cvt (768-831) ==
__global__ __launch_bounds__(256) void k1(Params p) {
  __shared__ short lds[32768];   // 64 KB
  __shared__ float red[64];
  const int blk = blockIdx.x;
  if (blk < 256) {
    vu_ring(blk & 63, blk >> 6, p, lds, red);
  } else if (blk < 512) {
    int q = blk - 256;
    g64<16, 0>(p.Wrb, 512, p.rmb, 512, p.swTb, 1024,
               (q >> 4) * 64, (q & 15) * 64, nullptr, nullptr, nullptr, nullptr, lds);
  } else if (blk < 768) {
    int q = blk - 512;
    g64<16, 0>(p.Wo2b, 512, p.rmb, 512, p.Ub, 1024,
               (q >> 4) * 64, (q & 15) * 64, nullptr, nullptr, nullptr, nullptr, lds);
  } else {
    // Wo1 f32 -> bf16 (consumed by k2): 1,048,576 floats = 131072 vec8 units
    int g = (blk - 768) * 256 + threadIdx.x;   // 16384 threads, 8 units each
    #pragma unroll
    for (int it = 0; it < 8; ++it) {
      long o = ((long)(g + it * 16384)) * 8;
      const float* src = p.Wo + (o >> 10) * 1536 + (o & 1023);
      float t[8];
      *(float4*)t       = *(const float4*)src;
      *(float4*)(t + 4) = *(const float4*)(src + 4);
      *(s16x8*)(p.Wo1b + o) = cvt8(t);
    }
  }
}

// ==== k2: Weff = Wo1 + U@s_wT^T (0-255) | gw2 + softmax (256-511) ====
__global__ __launch_bounds__(256) void k2(Params p) {
  __shared__ short lds[32768];
  const int blk = blockIdx.x;
  if (blk < 256) {
    g64<32, 1>(p.Ub, 1024, p.swTb, 1024, p.Weffb, 1024,
               (blk >> 4) * 64, (blk & 15) * 64, p.Wo1b, nullptr, nullptr, nullptr, lds);
  } else {
    int q = blk - 256;
    int wave = threadIdx.x >> 6;
    gw2_wave(q * 4 + wave, p);
    entity_wave(q * 4 + wave, p);
  }
}

// ================= k3: out = er @ Weff^T + bo + cf*gw2 =================
__global__ __launch_bounds__(256) void k3(Params p) {
  __shared__ short lds[32768];
  const int blk = blockIdx.x;
  g64<32, 2>(p.erb, 1024, p.Weffb, 1024, p.out, 1024,
             (blk >> 4) * 64, (blk & 15) * 64, nullptr, p.bo, p.cf, p.gw2, lds);
}

extern "C" void kernel_launch(void* const* d_in, const int* in_sizes, int n_in,
                              void* d_out, int out_size, void* d_ws, size_t ws_size,
                              hipStream_t stream) {
  (void)in_sizes; (void)n_in; (void)out_size; (void)ws_size;
  Params p;
  p.ment = (const float*)d_in[0];
  p.ents = (const int*)d_in[1];
  p.msk  = (const int*)d_in[2];
  p.rm   = (const float*)d_in[3];
  p.Wv   = (const float*)d_in[4];
  p.bv   = (const float*)d_in[5];
  p.Wu   = (const float*)d_in[6];
  p.bu   = (const float*)d_in[7];
  p.Wa   = (const float*)d_in[8];
  // d_in[9] = ba: drops out (softmax shift-invariance)
  p.Wr   = (const float*)d_in[10];
  p.br   = (const float*)d_in[11];
  p.Wo   = (const float*)d_in[12];
  p.bo   = (const float*)d_in[13];
  p.out  = (float*)d_out;

  char* w = (char*)d_ws;
  auto alloc = [&](size_t bytes) {
    void* q = (void*)w; w += (bytes + 255) & ~(size_t)255; return q;
  };
  p.Xb    = (short*)alloc((size_t)2048 * 1024 * 2);  // X bf16
  p.Wvb   = (short*)alloc((size_t)256 * 1024 * 2);
  p.Wub   = (short*)alloc((size_t)256 * 1024 * 2);
  p.rmb   = (short*)alloc((size_t)1024 * 512 * 2);
  p.Wrb   = (short*)alloc((size_t)1024 * 512 * 2);
  p.Wo2b  = (short*)alloc((size_t)1024 * 512 * 2);
  p.Wo1b  = (short*)alloc((size_t)1024 * 1024 * 2);  // Wo1 bf16 (dense)
  p.swTb  = (short*)alloc((size_t)1024 * 1024 * 2);  // s_wT[h,r] bf16
  p.Ub    = (short*)alloc((size_t)1024 * 1024 * 2);  // U[h,r] bf16
  p.Weffb = (short*)alloc((size_t)1024 * 1024 * 2);  // Wo1 + U@s_wT^T bf16
  p.erb   = (short*)alloc((size_t)1024 * 1024 * 2);  // entity reprs bf16
  p.wpart = (float*)alloc((size_t)4 * 2048 * 4);     // gate partials
  p.cf    = (float*)alloc((size_t)1024 * 4);         // er . br
  p.gw2   = (float*)alloc((size_t)1024 * 4);         // rowsum(U)

  k0<<<512, 256, 0, stream>>>(p);
  k1<<<832, 256, 0, stream>>>(p);
  k2<<<512, 256, 0, stream>>>(p);
  k3<<<256, 256, 0, stream>>>(p);
}